// Round 2
// baseline (748.215 us; speedup 1.0000x reference)
//
#include <hip/hip_runtime.h>

#define EPS 1e-5f
#define FIXSCALE 8388608.0f   // 2^23 fixed-point for degree accumulation
#define NBK 64                // degree buckets (qc clamped)

typedef __attribute__((ext_vector_type(8))) short short8;
typedef __attribute__((ext_vector_type(4))) short short4v;
typedef __attribute__((ext_vector_type(4))) float float4v;
typedef __attribute__((ext_vector_type(2))) float float2v;
typedef __attribute__((ext_vector_type(8))) unsigned short ushort8;
typedef __attribute__((ext_vector_type(4))) unsigned int uint4v;

#if __has_builtin(__builtin_nontemporal_load)
#define NT_LOAD(p) __builtin_nontemporal_load(p)
#else
#define NT_LOAD(p) (*(p))
#endif

__device__ __forceinline__ unsigned short f2b(float f) {
    union { float f; unsigned u; } v; v.f = f;
    unsigned r = v.u + 0x7FFF + ((v.u >> 16) & 1);   // RNE
    return (unsigned short)(r >> 16);
}
__device__ __forceinline__ float b2f(unsigned short u) {
    union { unsigned u; float f; } v; v.u = ((unsigned)u) << 16;
    return v.f;
}

__device__ __forceinline__ int qbucket(int cnt) {
    int qc = ((cnt + 4) & ~3) >> 2;
    return qc < NBK - 1 ? qc : NBK - 1;
}

// ---------------- setup kernels ----------------

// ONE atomic per edge; combo padded to 1 node / 64B line
__global__ __launch_bounds__(256) void rank_kernel(const int* __restrict__ dst,
                                                   const float* __restrict__ w,
                                                   unsigned long long* __restrict__ combo,
                                                   int* __restrict__ rank, int E) {
    int e = blockIdx.x * 256 + threadIdx.x;
    if (e < E) {
        int d = dst[e];
        unsigned long long pack = (1ULL << 32) | (unsigned long long)(unsigned)(w[e] * FIXSCALE);
        unsigned long long old = atomicAdd(&combo[(size_t)d * 8], pack);
        rank[e] = (int)(old >> 32);
    }
}

// dinv per original node (parallel, grid-stride)
__global__ __launch_bounds__(256) void dinv_kernel(const unsigned long long* __restrict__ combo,
                                                   float* __restrict__ dinv, int n) {
    int d = blockIdx.x * 256 + threadIdx.x;
    if (d < n) {
        float degv = (float)(unsigned)(combo[(size_t)d * 8] & 0xffffffffULL) * (1.0f / FIXSCALE);
        dinv[d] = rsqrtf(degv + 1.0f);
    }
}

// ---- contention-free counting sort by row quad-count (descending) ----

// per-block LDS histogram -> blockhist; LDS atomics only
__global__ __launch_bounds__(256) void bin_hist_kernel(const unsigned long long* __restrict__ combo,
                                                       int* __restrict__ blockhist, int n) {
    __shared__ int lh[NBK];
    int t = threadIdx.x;
    if (t < NBK) lh[t] = 0;
    __syncthreads();
    int d = blockIdx.x * 256 + t;
    if (d < n) {
        int cnt = (int)(combo[(size_t)d * 8] >> 32);
        atomicAdd(&lh[qbucket(cnt)], 1);
    }
    __syncthreads();
    if (t < NBK) blockhist[blockIdx.x * NBK + t] = lh[t];
}

// one block PER BUCKET: exclusive prefix of its per-block counts + bucket total
__global__ __launch_bounds__(256) void bin_prescan_kernel(const int* __restrict__ blockhist,
                                                          int* __restrict__ blockpre,
                                                          int* __restrict__ tot, int nblk) {
    int bkt = blockIdx.x;
    int t = threadIdx.x, lane = t & 63, w = t >> 6;
    __shared__ int wsum[4];
    __shared__ int s_carry;
    if (t == 0) s_carry = 0;
    __syncthreads();
    for (int base = 0; base < nblk; base += 256) {
        int i = base + t;
        int v = (i < nblk) ? blockhist[i * NBK + bkt] : 0;
        int x = v;
        for (int off = 1; off < 64; off <<= 1) {
            int u = __shfl_up(x, off);
            if (lane >= off) x += u;
        }
        if (lane == 63) wsum[w] = x;
        __syncthreads();
        if (t == 0) {
            int a = wsum[0];
            wsum[0] = 0;
            for (int k = 1; k < 4; ++k) { int b = wsum[k]; wsum[k] = a; a += b; }
            wsum[0] = 0;
        }
        __syncthreads();
        int carry = s_carry;
        int woff = wsum[w];
        if (i < nblk) blockpre[i * NBK + bkt] = carry + woff + x - v;
        __syncthreads();
        if (t == 255) s_carry = carry + woff + x;
        __syncthreads();
    }
    if (t == 0) tot[bkt] = s_carry;
}

// single wave: base[b] = sum_{b' > b} tot[b']  (descending buckets first)
__global__ __launch_bounds__(64) void bin_suffix_kernel(const int* __restrict__ tot,
                                                        int* __restrict__ base) {
    int t = threadIdx.x;
    int v = tot[t];
    int s = v;
    for (int off = 1; off < 64; off <<= 1) {
        int u = __shfl_down(s, off);
        if (t + off < 64) s += u;
    }
    base[t] = s - v;
}

// assign slots via LDS cursors; also record each slot's padded quad length (linear later)
__global__ __launch_bounds__(256) void bin_scatter_kernel(const unsigned long long* __restrict__ combo,
                                                          const int* __restrict__ base,
                                                          const int* __restrict__ blockpre,
                                                          int* __restrict__ perm,
                                                          int* __restrict__ posod,
                                                          int* __restrict__ qlen, int n) {
    __shared__ int lcur[NBK];
    int t = threadIdx.x;
    if (t < NBK) lcur[t] = base[t] + blockpre[blockIdx.x * NBK + t];
    __syncthreads();
    int d = blockIdx.x * 256 + t;
    if (d < n) {
        int cnt = (int)(combo[(size_t)d * 8] >> 32);
        int pos = atomicAdd(&lcur[qbucket(cnt)], 1);
        perm[pos] = d;
        posod[d] = pos;
        qlen[pos] = (cnt + 4) & ~3;
    }
}

// row_ptr over permuted slots: linear scan of qlen (single block, coalesced)
__global__ __launch_bounds__(1024) void scan_kernel(const int* __restrict__ qlen,
                                                    int* __restrict__ row_ptr, int n) {
    int tid = threadIdx.x, lane = tid & 63, w = tid >> 6;
    __shared__ int wsum[16];
    __shared__ int s_carry;
    if (tid == 0) s_carry = 0;
    __syncthreads();
    for (int base = 0; base < n; base += 1024) {
        int i = base + tid;
        int v = (i < n) ? qlen[i] : 0;
        int x = v;
        for (int off = 1; off < 64; off <<= 1) {
            int t = __shfl_up(x, off);
            if (lane >= off) x += t;
        }
        if (lane == 63) wsum[w] = x;
        __syncthreads();
        if (w == 0 && lane < 16) {
            int s = wsum[lane];
            for (int off = 1; off < 16; off <<= 1) {
                int t = __shfl_up(s, off, 16);
                if (lane >= off) s += t;
            }
            wsum[lane] = s;
        }
        __syncthreads();
        int carry = s_carry;
        int woff = (w > 0) ? wsum[w - 1] : 0;
        if (i < n) row_ptr[i + 1] = carry + woff + x;
        __syncthreads();
        if (tid == 0) s_carry = carry + wsum[15];
        __syncthreads();
    }
    if (tid == 0) row_ptr[0] = 0;
}

// self-edge (slot 0, weight dinv^2, src = own slot) + zero-weight pads
__global__ __launch_bounds__(256) void selfpad_kernel(const unsigned long long* __restrict__ combo,
                                                      const int* __restrict__ row_ptr,
                                                      const int* __restrict__ posod,
                                                      const float* __restrict__ dinv,
                                                      unsigned int* __restrict__ edge, int n) {
    int d = blockIdx.x * 256 + threadIdx.x;
    if (d < n) {
        int cnt = (int)(combo[(size_t)d * 8] >> 32);
        int slot = posod[d];
        int j0 = row_ptr[slot], j1 = row_ptr[slot + 1];
        float di = dinv[d];
        edge[j0] = ((unsigned)f2b(di * di) << 16) | (unsigned)slot;
        for (int j = j0 + 1 + cnt; j < j1; ++j) edge[j] = (unsigned)slot;  // w = +0
    }
}

// atomic-free scatter into permuted CSR; record = wn(bf16)<<16 | srcslot(u16)
__global__ __launch_bounds__(256) void scatter2_kernel(
    const int* __restrict__ src, const int* __restrict__ dst,
    const float* __restrict__ w, const int* __restrict__ rank,
    const int* __restrict__ row_ptr, const int* __restrict__ posod,
    const float* __restrict__ dinv, unsigned int* __restrict__ edge, int E) {
    int e = blockIdx.x * 256 + threadIdx.x;
    if (e < E) {
        int d = dst[e], s = src[e];
        float wn = dinv[s] * w[e] * dinv[d];
        edge[row_ptr[posod[d]] + 1 + rank[e]] = ((unsigned)f2b(wn) << 16) | (unsigned)posod[s];
    }
}

// node f32 [N][F] (original order) -> bf16 slice-major [F/32][n][32] in SLOT order
__global__ __launch_bounds__(256) void cast_sliced_kernel(const float* __restrict__ in,
                                                          const int* __restrict__ perm,
                                                          unsigned short* __restrict__ out,
                                                          int n, int F) {
    int idx = blockIdx.x * 256 + threadIdx.x;
    if (idx < n * (F / 4)) {
        int f4 = idx * 4;
        int slot = f4 / F, f = f4 - slot * F;
        float4 v = *(const float4*)&in[(size_t)perm[slot] * F + f];
        short4v s = (short4v){(short)f2b(v.x), (short)f2b(v.y), (short)f2b(v.z), (short)f2b(v.w)};
        *(short4v*)&out[((size_t)(f >> 5) * n + slot) * 32 + (f & 31)] = s;
    }
}

__global__ __launch_bounds__(256) void wtrans_kernel(const float* __restrict__ W,
                                                     unsigned short* __restrict__ Wt,
                                                     int K, int Nc) {
    int o = blockIdx.x * 256 + threadIdx.x;
    if (o < K * Nc) {
        int n = o / K, k = o - n * K;
        Wt[o] = f2b(W[(size_t)k * Nc + n]);
    }
}

// ---------------- bf16 MFMA GEMM, full-N strip: C[M,256] = A[M,K](bf16) @ Bt[256,K]^T ----

#define GST 88

template <bool SLICEOUT>
__global__ __launch_bounds__(256) void gemm_n256(const unsigned short* __restrict__ A,
                                                 const unsigned short* __restrict__ Bt,
                                                 unsigned short* __restrict__ Cout,
                                                 const float* __restrict__ bias,
                                                 int M, int K) {
    __shared__ __align__(16) short As[64 * GST];
    __shared__ __align__(16) short Bs[256 * GST];
    int t = threadIdx.x;
    int lane = t & 63, w = t >> 6;
    int quad = lane >> 4, l16 = lane & 15;
    int row0 = blockIdx.x * 64;

    float4v acc[16];
#pragma unroll
    for (int c = 0; c < 16; ++c) acc[c] = (float4v){0.f, 0.f, 0.f, 0.f};

    int arow = t >> 2, ak16 = (t & 3) * 16;
    int bcol0 = t >> 2, bko = (t & 3) * 16;

    for (int k_outer = 0; k_outer < K; k_outer += 64) {
        bool rowok = (row0 + arow) < M;
        const unsigned short* ap = &A[(size_t)(row0 + arow) * K + k_outer + ak16];
        uint4 z = make_uint4(0, 0, 0, 0);
        uint4 u0 = rowok ? *(const uint4*)ap : z;
        uint4 u1 = rowok ? *(const uint4*)(ap + 8) : z;
        *(uint4*)&As[arow * GST + ak16] = u0;
        *(uint4*)&As[arow * GST + ak16 + 8] = u1;
#pragma unroll
        for (int cb = 0; cb < 4; ++cb) {
            int col = bcol0 + 64 * cb;
            const unsigned short* bp = &Bt[(size_t)col * K + k_outer + bko];
#pragma unroll
            for (int u = 0; u < 2; ++u)
                *(uint4*)&Bs[col * GST + bko + u * 8] = *(const uint4*)&bp[u * 8];
        }
        __syncthreads();
#pragma unroll
        for (int k0 = 0; k0 < 64; k0 += 32) {
            short8 a = *(const short8*)&As[(w * 16 + l16) * GST + k0 + quad * 8];
#pragma unroll
            for (int c = 0; c < 16; ++c) {
                short8 b = *(const short8*)&Bs[(c * 16 + l16) * GST + k0 + quad * 8];
                acc[c] = __builtin_amdgcn_mfma_f32_16x16x32_bf16(a, b, acc[c], 0, 0, 0);
            }
        }
        __syncthreads();
    }
#pragma unroll
    for (int c = 0; c < 16; ++c) {
        int col = c * 16 + l16;
        float bcol = (!SLICEOUT) ? bias[col] : 0.0f;
#pragma unroll
        for (int r = 0; r < 4; ++r) {
            int row = row0 + w * 16 + quad * 4 + r;
            if (row < M) {
                if (SLICEOUT)
                    Cout[((size_t)(c >> 1) * M + row) * 32 + ((c & 1) << 4) + l16] = f2b(acc[c][r]);
                else
                    Cout[(size_t)row * 256 + col] = f2b(acc[c][r] + bcol);
            }
        }
    }
}

// ---------------- aggregation: 4-lane group per slot, slice-major table, LDS edges ------
// Slots degree-sorted (descending): 16 groups per wave see near-equal row lengths.
// slice = blockIdx & mask -> XCD-resident 3.2MB slice. 32 KB LDS edge stage.
//
// Inner loop is a latency-bound random 64B gather from L2 (HBM 11%, VALU 32%,
// nothing saturated). Fix: explicit MLP — two 2-quad batches (A/B) double-
// buffered so 8 table loads are always in flight while the other batch's 8
// edges are unpacked+FMA'd.

#define CAPQ 2048   // 8192 edges, 32 KB LDS

template <int CSH>
__global__ __launch_bounds__(256) void agg_grp(
    const unsigned short* __restrict__ tab0, const int* __restrict__ row_ptr,
    const unsigned int* __restrict__ edge, unsigned short* __restrict__ outb, int n) {
    __shared__ uint4v eq[CAPQ];
    int b = blockIdx.x;
    int s = b & ((1 << CSH) - 1);
    int grp = b >> CSH;
    int t = threadIdx.x;
    int d0 = grp * 64;
    int d = d0 + (t >> 2);

    const uint4v* e4p = (const uint4v*)edge;
    int qbase = row_ptr[d0] >> 2;
    int dmax = d0 + 64 < n ? d0 + 64 : n;
    int qcnt = (row_ptr[dmax] >> 2) - qbase;
    int qstage = qcnt < CAPQ ? qcnt : CAPQ;
    for (int i = t; i < qstage; i += 256) eq[i] = NT_LOAD(&e4p[qbase + i]);
    __syncthreads();

    if (d >= n) return;
    int fo = (t & 3) << 3;                    // feature offset within the 32-wide slice
    const unsigned short* tab = tab0 + (size_t)s * n * 32;

    int j = row_ptr[d] >> 2, j1 = row_ptr[d + 1] >> 2;
    int jmid = j1 < qbase + CAPQ ? j1 : qbase + CAPQ;

    float2v a2[4];
#pragma unroll
    for (int k = 0; k < 4; ++k) a2[k] = (float2v){0.f, 0.f};

    // single-edge unpack+fma (used by compute phases and tails)
    auto compq = [&](unsigned e, uint4 r) {
        float wq = __int_as_float((int)(e & 0xffff0000u));
        float2v w2 = {wq, wq};
        float2v f0 = {__uint_as_float(r.x << 16), __uint_as_float(r.x & 0xffff0000u)};
        float2v f1 = {__uint_as_float(r.y << 16), __uint_as_float(r.y & 0xffff0000u)};
        float2v f2 = {__uint_as_float(r.z << 16), __uint_as_float(r.z & 0xffff0000u)};
        float2v f3 = {__uint_as_float(r.w << 16), __uint_as_float(r.w & 0xffff0000u)};
        a2[0] += f0 * w2;
        a2[1] += f1 * w2;
        a2[2] += f2 * w2;
        a2[3] += f3 * w2;
    };
    // combined load+compute for tails (1 quad)
    auto process = [&](uint4v e4) {
#pragma unroll
        for (int u = 0; u < 4; ++u) {
            unsigned e = e4[u];
            unsigned off = ((e & 0xffffu) << 5) + (unsigned)fo;
            uint4 rr = *(const uint4*)(tab + off);
            compq(e, rr);
        }
    };
    // issue phase: 2 quads -> 8 independent 16B loads in flight
    auto issue2 = [&](int jj, uint4v& q0, uint4v& q1, uint4* rr) {
        q0 = eq[jj - qbase];
        q1 = eq[jj + 1 - qbase];
#pragma unroll
        for (int u = 0; u < 4; ++u)
            rr[u] = *(const uint4*)(tab + (((q0[u] & 0xffffu) << 5) + (unsigned)fo));
#pragma unroll
        for (int u = 0; u < 4; ++u)
            rr[4 + u] = *(const uint4*)(tab + (((q1[u] & 0xffffu) << 5) + (unsigned)fo));
    };
    // compute phase: consume 2 quads from registers
    auto comp2 = [&](uint4v q0, uint4v q1, const uint4* rr) {
#pragma unroll
        for (int u = 0; u < 4; ++u) compq(q0[u], rr[u]);
#pragma unroll
        for (int u = 0; u < 4; ++u) compq(q1[u], rr[4 + u]);
    };

    uint4v qA0, qA1, qB0, qB1;
    uint4 rrA[8], rrB[8];
    int nq2 = (jmid - j) >> 1;                // number of 2-quad batches in LDS window
    if (nq2 > 0) {
        issue2(j, qA0, qA1, rrA);
        int bb = 1;
        for (; bb + 1 < nq2; bb += 2) {
            issue2(j + 2 * bb, qB0, qB1, rrB);
            comp2(qA0, qA1, rrA);
            issue2(j + 2 * bb + 2, qA0, qA1, rrA);
            comp2(qB0, qB1, rrB);
        }
        if (bb < nq2) {
            issue2(j + 2 * bb, qB0, qB1, rrB);
            comp2(qA0, qA1, rrA);
            comp2(qB0, qB1, rrB);
        } else {
            comp2(qA0, qA1, rrA);
        }
        j += 2 * nq2;
    }
    if (j < jmid) { process(eq[j - qbase]); ++j; }
    for (; j < j1; ++j) process(NT_LOAD(&e4p[j]));   // overflow fallback (first blocks only)

    ushort8 o;
#pragma unroll
    for (int k = 0; k < 4; ++k) {
        o[2 * k] = f2b(a2[k].x);
        o[2 * k + 1] = f2b(a2[k].y);
    }
    *(ushort8*)(outb + ((size_t)d << (5 + CSH)) + (s << 5) + fo) = o;
}

// ---------------- bias + LayerNorm + residual + ReLU (bf16 in, bf16 out) ----------------

__global__ __launch_bounds__(256) void ln_res_relu(
    const unsigned short* __restrict__ preln, const float* __restrict__ bias,
    const float* __restrict__ g, const float* __restrict__ lb,
    const unsigned short* __restrict__ res, unsigned short* __restrict__ out, int n) {
    int wv = __builtin_amdgcn_readfirstlane(threadIdx.x >> 6);
    int d = blockIdx.x * 4 + wv;
    if (d >= n) return;
    int l = threadIdx.x & 63;
    int fo = l * 4;
    ushort4 pv = *(const ushort4*)&preln[(size_t)d * 256 + fo];
    float4 bb = *(const float4*)&bias[fo];
    float v[4] = {b2f(pv.x) + bb.x, b2f(pv.y) + bb.y, b2f(pv.z) + bb.z, b2f(pv.w) + bb.w};
    float s4 = v[0] + v[1] + v[2] + v[3];
#pragma unroll
    for (int off = 1; off < 64; off <<= 1) s4 += __shfl_xor(s4, off);
    float mu = s4 * (1.0f / 256.0f);
    float dv[4];
    float qs = 0.f;
#pragma unroll
    for (int j = 0; j < 4; ++j) { dv[j] = v[j] - mu; qs += dv[j] * dv[j]; }
#pragma unroll
    for (int off = 1; off < 64; off <<= 1) qs += __shfl_xor(qs, off);
    float rs = rsqrtf(qs * (1.0f / 256.0f) + EPS);

    float4 gg = *(const float4*)&g[fo];
    float4 lbv = *(const float4*)&lb[fo];
    ushort4 rr4 = *(const ushort4*)&res[(size_t)d * 256 + fo];
    float ggv[4] = {gg.x, gg.y, gg.z, gg.w};
    float lbvv[4] = {lbv.x, lbv.y, lbv.z, lbv.w};
    float rrv[4] = {b2f(rr4.x), b2f(rr4.y), b2f(rr4.z), b2f(rr4.w)};
    ushort4 o;
    unsigned short* op = (unsigned short*)&o;
#pragma unroll
    for (int j = 0; j < 4; ++j) {
        float x = dv[j] * rs * ggv[j] + lbvv[j] + rrv[j];
        op[j] = f2b(x > 0.f ? x : 0.f);
    }
    *(ushort4*)&out[(size_t)d * 256 + fo] = o;
}

// ---------------- head ----------------

__global__ __launch_bounds__(256) void colsum_kernel(const unsigned short* __restrict__ x,
                                                     float* __restrict__ sums, int n) {
    int h = threadIdx.x;
    float acc = 0.0f;
    for (int r = blockIdx.x; r < n; r += gridDim.x) acc += b2f(x[(size_t)r * 256 + h]);
    atomicAdd(&sums[h], acc);
}

__global__ __launch_bounds__(64) void final_kernel(const float* __restrict__ sums,
                                                   const float* __restrict__ fcW,
                                                   const float* __restrict__ fcb,
                                                   float* __restrict__ out, float invN) {
    int lane = threadIdx.x;
    float p0 = 0.0f, p1 = 0.0f;
    for (int hh = lane; hh < 256; hh += 64) {
        float m = sums[hh];
        p0 += m * fcW[hh * 2 + 0];
        p1 += m * fcW[hh * 2 + 1];
    }
    for (int off = 32; off > 0; off >>= 1) {
        p0 += __shfl_down(p0, off);
        p1 += __shfl_down(p1, off);
    }
    if (lane == 0) {
        out[0] = p0 * invN + fcb[0];
        out[1] = p1 * invN + fcb[1];
    }
}

// ---------------- launch ----------------

extern "C" void kernel_launch(void* const* d_in, const int* in_sizes, int n_in,
                              void* d_out, int out_size, void* d_ws, size_t ws_size,
                              hipStream_t stream) {
    const float* node    = (const float*)d_in[0];
    const int*   edges   = (const int*)d_in[1];
    const float* eattr   = (const float*)d_in[2];
    const float* W1      = (const float*)d_in[3];
    const float* b1      = (const float*)d_in[4];
    const float* W_convs = (const float*)d_in[5];
    const float* b_convs = (const float*)d_in[6];
    const float* ln_g    = (const float*)d_in[7];
    const float* ln_b    = (const float*)d_in[8];
    const float* fc_W    = (const float*)d_in[9];
    const float* fc_b    = (const float*)d_in[10];
    float* out = (float*)d_out;

    const int H = in_sizes[4];           // 256
    const int F = in_sizes[3] / H;       // 128
    const int N = in_sizes[0] / F;       // 50000
    const int E = in_sizes[2];           // 1600000
    const int L = in_sizes[6] / H;       // 3

    const int* src = edges;
    const int* dst = edges + E;

    char* p = (char*)d_ws;
    auto alloc = [&](size_t bytes) {
        char* r = p;
        p += (bytes + 255) & ~(size_t)255;
        return r;
    };
    int nblk = (N + 255) / 256;
    // zeroed region: padded combo (64B/node) + colsums, contiguous
    unsigned long long* combo = (unsigned long long*)alloc((size_t)N * 64);
    float* colsums = (float*)alloc((size_t)H * 4);
    size_t zero_bytes = (size_t)((char*)colsums - (char*)combo) + (((size_t)H * 4 + 255) & ~(size_t)255);
    int*   blockhist = (int*)alloc((size_t)nblk * NBK * 4);
    int*   blockpre  = (int*)alloc((size_t)nblk * NBK * 4);
    int*   tot       = (int*)alloc((size_t)NBK * 4);
    int*   bbase     = (int*)alloc((size_t)NBK * 4);
    int*   perm    = (int*)alloc((size_t)N * 4);
    int*   posod   = (int*)alloc((size_t)N * 4);
    int*   qlen    = (int*)alloc((size_t)N * 4);
    float* dinv    = (float*)alloc((size_t)N * 4);
    int*   row_ptr = (int*)alloc((size_t)(N + 1) * 4);
    unsigned int* edge = (unsigned int*)alloc(((size_t)E + 4 * (size_t)N + 64) * 4);
    unsigned short* Wt1 = (unsigned short*)alloc((size_t)H * F * 2);
    unsigned short* Wtc = (unsigned short*)alloc((size_t)L * H * H * 2);
    unsigned short* xw  = (unsigned short*)alloc((size_t)N * H * 2);   // sliced [8][N][32]
    unsigned short* preln = (unsigned short*)alloc((size_t)N * H * 2); // row-major [N][256]
    unsigned short* bufA  = (unsigned short*)alloc((size_t)N * H * 2); // bf16 x
    unsigned short* bufB  = (unsigned short*)alloc((size_t)N * H * 2); // bf16 x
    // aliases (dead before their slabs' first real use):
    int*            rank  = (int*)xw;                     // E*4 <= N*H*2
    unsigned short* nodeb = preln;                        // sliced [4][N][32] = N*128 shorts
    unsigned short* aggn  = preln + (size_t)N * F;        // bf16 [N][128] row-major

    hipMemsetAsync(combo, 0, zero_bytes, stream);

    int gE = (E + 255) / 256;
    rank_kernel<<<gE, 256, 0, stream>>>(dst, eattr, combo, rank, E);
    dinv_kernel<<<nblk, 256, 0, stream>>>(combo, dinv, N);
    bin_hist_kernel<<<nblk, 256, 0, stream>>>(combo, blockhist, N);
    bin_prescan_kernel<<<NBK, 256, 0, stream>>>(blockhist, blockpre, tot, nblk);
    bin_suffix_kernel<<<1, 64, 0, stream>>>(tot, bbase);
    bin_scatter_kernel<<<nblk, 256, 0, stream>>>(combo, bbase, blockpre, perm, posod, qlen, N);
    scan_kernel<<<1, 1024, 0, stream>>>(qlen, row_ptr, N);
    selfpad_kernel<<<nblk, 256, 0, stream>>>(combo, row_ptr, posod, dinv, edge, N);
    scatter2_kernel<<<gE, 256, 0, stream>>>(src, dst, eattr, rank, row_ptr, posod, dinv, edge, E);

    cast_sliced_kernel<<<(N * (F / 4) + 255) / 256, 256, 0, stream>>>(node, perm, nodeb, N, F);
    wtrans_kernel<<<(F * H + 255) / 256, 256, 0, stream>>>(W1, Wt1, F, H);
    for (int i = 0; i < L; ++i)
        wtrans_kernel<<<(H * H + 255) / 256, 256, 0, stream>>>(
            W_convs + (size_t)i * H * H, Wtc + (size_t)i * H * H, H, H);

    int ngrp64 = (N + 63) / 64;
    int lngrid = (N + 3) / 4;
    int ggrid = (N + 63) / 64;

    // layer 1 (slot space): aggn = agg(node); x1 = aggn @ W1 + b1 (bf16)
    agg_grp<2><<<4 * ngrp64, 256, 0, stream>>>(nodeb, row_ptr, edge, aggn, N);
    gemm_n256<false><<<ggrid, 256, 0, stream>>>(aggn, Wt1, bufA, b1, N, F);

    unsigned short* x = bufA;
    unsigned short* other = bufB;
    for (int i = 0; i < L; ++i) {
        gemm_n256<true><<<ggrid, 256, 0, stream>>>(x, Wtc + (size_t)i * H * H, xw, nullptr, N, H);
        agg_grp<3><<<8 * ngrp64, 256, 0, stream>>>(xw, row_ptr, edge, preln, N);
        ln_res_relu<<<lngrid, 256, 0, stream>>>(preln, b_convs + (size_t)i * H,
                                                ln_g + (size_t)i * H, ln_b + (size_t)i * H,
                                                x, other, N);
        unsigned short* t = x; x = other; other = t;
    }

    colsum_kernel<<<256, 256, 0, stream>>>(x, colsums, N);
    final_kernel<<<1, 64, 0, stream>>>(colsums, fc_W, fc_b, out, 1.0f / (float)N);
}

// Round 4
// 712.820 us; speedup vs baseline: 1.0497x; 1.0497x over previous
//
#include <hip/hip_runtime.h>

#define EPS 1e-5f
#define FIXSCALE 8388608.0f   // 2^23 fixed-point for degree accumulation
#define NBK 64                // degree buckets (qc clamped)

typedef __attribute__((ext_vector_type(8))) short short8;
typedef __attribute__((ext_vector_type(4))) short short4v;
typedef __attribute__((ext_vector_type(4))) float float4v;
typedef __attribute__((ext_vector_type(2))) float float2v;
typedef __attribute__((ext_vector_type(8))) unsigned short ushort8;
typedef __attribute__((ext_vector_type(4))) unsigned int uint4v;

#if __has_builtin(__builtin_nontemporal_load)
#define NT_LOAD(p) __builtin_nontemporal_load(p)
#else
#define NT_LOAD(p) (*(p))
#endif

__device__ __forceinline__ unsigned short f2b(float f) {
    union { float f; unsigned u; } v; v.f = f;
    unsigned r = v.u + 0x7FFF + ((v.u >> 16) & 1);   // RNE
    return (unsigned short)(r >> 16);
}
__device__ __forceinline__ float b2f(unsigned short u) {
    union { unsigned u; float f; } v; v.u = ((unsigned)u) << 16;
    return v.f;
}

__device__ __forceinline__ int qbucket(int cnt) {
    int qc = ((cnt + 4) & ~3) >> 2;
    return qc < NBK - 1 ? qc : NBK - 1;
}

// ---------------- setup kernels ----------------

// ONE atomic per edge; combo padded to 1 node / 64B line
__global__ __launch_bounds__(256) void rank_kernel(const int* __restrict__ dst,
                                                   const float* __restrict__ w,
                                                   unsigned long long* __restrict__ combo,
                                                   int* __restrict__ rank, int E) {
    int e = blockIdx.x * 256 + threadIdx.x;
    if (e < E) {
        int d = dst[e];
        unsigned long long pack = (1ULL << 32) | (unsigned long long)(unsigned)(w[e] * FIXSCALE);
        unsigned long long old = atomicAdd(&combo[(size_t)d * 8], pack);
        rank[e] = (int)(old >> 32);
    }
}

// dinv per original node (parallel, grid-stride)
__global__ __launch_bounds__(256) void dinv_kernel(const unsigned long long* __restrict__ combo,
                                                   float* __restrict__ dinv, int n) {
    int d = blockIdx.x * 256 + threadIdx.x;
    if (d < n) {
        float degv = (float)(unsigned)(combo[(size_t)d * 8] & 0xffffffffULL) * (1.0f / FIXSCALE);
        dinv[d] = rsqrtf(degv + 1.0f);
    }
}

// ---- contention-free counting sort by row quad-count (descending) ----

// per-block LDS histogram -> blockhist; LDS atomics only
__global__ __launch_bounds__(256) void bin_hist_kernel(const unsigned long long* __restrict__ combo,
                                                       int* __restrict__ blockhist, int n) {
    __shared__ int lh[NBK];
    int t = threadIdx.x;
    if (t < NBK) lh[t] = 0;
    __syncthreads();
    int d = blockIdx.x * 256 + t;
    if (d < n) {
        int cnt = (int)(combo[(size_t)d * 8] >> 32);
        atomicAdd(&lh[qbucket(cnt)], 1);
    }
    __syncthreads();
    if (t < NBK) blockhist[blockIdx.x * NBK + t] = lh[t];
}

// one block PER BUCKET: exclusive prefix of its per-block counts + bucket total
__global__ __launch_bounds__(256) void bin_prescan_kernel(const int* __restrict__ blockhist,
                                                          int* __restrict__ blockpre,
                                                          int* __restrict__ tot, int nblk) {
    int bkt = blockIdx.x;
    int t = threadIdx.x, lane = t & 63, w = t >> 6;
    __shared__ int wsum[4];
    __shared__ int s_carry;
    if (t == 0) s_carry = 0;
    __syncthreads();
    for (int base = 0; base < nblk; base += 256) {
        int i = base + t;
        int v = (i < nblk) ? blockhist[i * NBK + bkt] : 0;
        int x = v;
        for (int off = 1; off < 64; off <<= 1) {
            int u = __shfl_up(x, off);
            if (lane >= off) x += u;
        }
        if (lane == 63) wsum[w] = x;
        __syncthreads();
        if (t == 0) {
            int a = wsum[0];
            wsum[0] = 0;
            for (int k = 1; k < 4; ++k) { int b = wsum[k]; wsum[k] = a; a += b; }
            wsum[0] = 0;
        }
        __syncthreads();
        int carry = s_carry;
        int woff = wsum[w];
        if (i < nblk) blockpre[i * NBK + bkt] = carry + woff + x - v;
        __syncthreads();
        if (t == 255) s_carry = carry + woff + x;
        __syncthreads();
    }
    if (t == 0) tot[bkt] = s_carry;
}

// single wave: base[b] = sum_{b' > b} tot[b']  (descending buckets first)
__global__ __launch_bounds__(64) void bin_suffix_kernel(const int* __restrict__ tot,
                                                        int* __restrict__ base) {
    int t = threadIdx.x;
    int v = tot[t];
    int s = v;
    for (int off = 1; off < 64; off <<= 1) {
        int u = __shfl_down(s, off);
        if (t + off < 64) s += u;
    }
    base[t] = s - v;
}

// assign slots via LDS cursors; also record each slot's padded quad length (linear later)
__global__ __launch_bounds__(256) void bin_scatter_kernel(const unsigned long long* __restrict__ combo,
                                                          const int* __restrict__ base,
                                                          const int* __restrict__ blockpre,
                                                          int* __restrict__ perm,
                                                          int* __restrict__ posod,
                                                          int* __restrict__ qlen, int n) {
    __shared__ int lcur[NBK];
    int t = threadIdx.x;
    if (t < NBK) lcur[t] = base[t] + blockpre[blockIdx.x * NBK + t];
    __syncthreads();
    int d = blockIdx.x * 256 + t;
    if (d < n) {
        int cnt = (int)(combo[(size_t)d * 8] >> 32);
        int pos = atomicAdd(&lcur[qbucket(cnt)], 1);
        perm[pos] = d;
        posod[d] = pos;
        qlen[pos] = (cnt + 4) & ~3;
    }
}

// ---- row_ptr over permuted slots: 3-kernel multi-block scan (was 1-block serial) ----

// block-local inclusive scan of qlen -> row_ptr[i+1]; block totals -> bsum
__global__ __launch_bounds__(1024) void scan_local_kernel(const int* __restrict__ qlen,
                                                          int* __restrict__ row_ptr,
                                                          int* __restrict__ bsum, int n) {
    int tid = threadIdx.x, lane = tid & 63, w = tid >> 6;
    __shared__ int wsum[16];
    int i = blockIdx.x * 1024 + tid;
    int v = (i < n) ? qlen[i] : 0;
    int x = v;
    for (int off = 1; off < 64; off <<= 1) {
        int t = __shfl_up(x, off);
        if (lane >= off) x += t;
    }
    if (lane == 63) wsum[w] = x;
    __syncthreads();
    if (w == 0 && lane < 16) {
        int s = wsum[lane];
        for (int off = 1; off < 16; off <<= 1) {
            int t = __shfl_up(s, off, 16);
            if (lane >= off) s += t;
        }
        wsum[lane] = s;
    }
    __syncthreads();
    int woff = (w > 0) ? wsum[w - 1] : 0;
    if (i < n) row_ptr[i + 1] = woff + x;
    if (tid == 0) bsum[blockIdx.x] = wsum[15];
}

// single wave: exclusive scan of block sums (carry loop handles nb > 64); row_ptr[0] = 0
__global__ __launch_bounds__(64) void scan_mid_kernel(int* __restrict__ bsum,
                                                      int* __restrict__ row_ptr, int nb) {
    int t = threadIdx.x;
    int carry = 0;
    for (int base = 0; base < nb; base += 64) {
        int idx = base + t;
        int v = (idx < nb) ? bsum[idx] : 0;
        int x = v;
        for (int off = 1; off < 64; off <<= 1) {
            int u = __shfl_up(x, off);
            if (t >= off) x += u;
        }
        if (idx < nb) bsum[idx] = carry + x - v;
        carry += __shfl(x, 63);
    }
    if (t == 0) row_ptr[0] = 0;
}

// add block offsets
__global__ __launch_bounds__(1024) void scan_add_kernel(const int* __restrict__ bsum,
                                                        int* __restrict__ row_ptr, int n) {
    int i = blockIdx.x * 1024 + threadIdx.x;
    if (i < n) row_ptr[i + 1] += bsum[blockIdx.x];
}

// self-edge (slot 0, weight dinv^2, src = own slot) + zero-weight pads
__global__ __launch_bounds__(256) void selfpad_kernel(const unsigned long long* __restrict__ combo,
                                                      const int* __restrict__ row_ptr,
                                                      const int* __restrict__ posod,
                                                      const float* __restrict__ dinv,
                                                      unsigned int* __restrict__ edge, int n) {
    int d = blockIdx.x * 256 + threadIdx.x;
    if (d < n) {
        int cnt = (int)(combo[(size_t)d * 8] >> 32);
        int slot = posod[d];
        int j0 = row_ptr[slot], j1 = row_ptr[slot + 1];
        float di = dinv[d];
        edge[j0] = ((unsigned)f2b(di * di) << 16) | (unsigned)slot;
        for (int j = j0 + 1 + cnt; j < j1; ++j) edge[j] = (unsigned)slot;  // w = +0
    }
}

// atomic-free scatter into permuted CSR; record = wn(bf16)<<16 | srcslot(u16)
__global__ __launch_bounds__(256) void scatter2_kernel(
    const int* __restrict__ src, const int* __restrict__ dst,
    const float* __restrict__ w, const int* __restrict__ rank,
    const int* __restrict__ row_ptr, const int* __restrict__ posod,
    const float* __restrict__ dinv, unsigned int* __restrict__ edge, int E) {
    int e = blockIdx.x * 256 + threadIdx.x;
    if (e < E) {
        int d = dst[e], s = src[e];
        float wn = dinv[s] * w[e] * dinv[d];
        edge[row_ptr[posod[d]] + 1 + rank[e]] = ((unsigned)f2b(wn) << 16) | (unsigned)posod[s];
    }
}

// node f32 [N][F] (original order) -> bf16 slice-major [F/32][n][32] in SLOT order
__global__ __launch_bounds__(256) void cast_sliced_kernel(const float* __restrict__ in,
                                                          const int* __restrict__ perm,
                                                          unsigned short* __restrict__ out,
                                                          int n, int F) {
    int idx = blockIdx.x * 256 + threadIdx.x;
    if (idx < n * (F / 4)) {
        int f4 = idx * 4;
        int slot = f4 / F, f = f4 - slot * F;
        float4 v = *(const float4*)&in[(size_t)perm[slot] * F + f];
        short4v s = (short4v){(short)f2b(v.x), (short)f2b(v.y), (short)f2b(v.z), (short)f2b(v.w)};
        *(short4v*)&out[((size_t)(f >> 5) * n + slot) * 32 + (f & 31)] = s;
    }
}

__global__ __launch_bounds__(256) void wtrans_kernel(const float* __restrict__ W,
                                                     unsigned short* __restrict__ Wt,
                                                     int K, int Nc) {
    int o = blockIdx.x * 256 + threadIdx.x;
    if (o < K * Nc) {
        int n = o / K, k = o - n * K;
        Wt[o] = f2b(W[(size_t)k * Nc + n]);
    }
}

// ---------------- bf16 MFMA GEMM, full-N strip: C[M,256] = A[M,K](bf16) @ Bt[256,K]^T ----

#define GST 88

template <bool SLICEOUT>
__global__ __launch_bounds__(256) void gemm_n256(const unsigned short* __restrict__ A,
                                                 const unsigned short* __restrict__ Bt,
                                                 unsigned short* __restrict__ Cout,
                                                 const float* __restrict__ bias,
                                                 int M, int K) {
    __shared__ __align__(16) short As[64 * GST];
    __shared__ __align__(16) short Bs[256 * GST];
    int t = threadIdx.x;
    int lane = t & 63, w = t >> 6;
    int quad = lane >> 4, l16 = lane & 15;
    int row0 = blockIdx.x * 64;

    float4v acc[16];
#pragma unroll
    for (int c = 0; c < 16; ++c) acc[c] = (float4v){0.f, 0.f, 0.f, 0.f};

    int arow = t >> 2, ak16 = (t & 3) * 16;
    int bcol0 = t >> 2, bko = (t & 3) * 16;

    for (int k_outer = 0; k_outer < K; k_outer += 64) {
        bool rowok = (row0 + arow) < M;
        const unsigned short* ap = &A[(size_t)(row0 + arow) * K + k_outer + ak16];
        uint4 z = make_uint4(0, 0, 0, 0);
        uint4 u0 = rowok ? *(const uint4*)ap : z;
        uint4 u1 = rowok ? *(const uint4*)(ap + 8) : z;
        *(uint4*)&As[arow * GST + ak16] = u0;
        *(uint4*)&As[arow * GST + ak16 + 8] = u1;
#pragma unroll
        for (int cb = 0; cb < 4; ++cb) {
            int col = bcol0 + 64 * cb;
            const unsigned short* bp = &Bt[(size_t)col * K + k_outer + bko];
#pragma unroll
            for (int u = 0; u < 2; ++u)
                *(uint4*)&Bs[col * GST + bko + u * 8] = *(const uint4*)&bp[u * 8];
        }
        __syncthreads();
#pragma unroll
        for (int k0 = 0; k0 < 64; k0 += 32) {
            short8 a = *(const short8*)&As[(w * 16 + l16) * GST + k0 + quad * 8];
#pragma unroll
            for (int c = 0; c < 16; ++c) {
                short8 b = *(const short8*)&Bs[(c * 16 + l16) * GST + k0 + quad * 8];
                acc[c] = __builtin_amdgcn_mfma_f32_16x16x32_bf16(a, b, acc[c], 0, 0, 0);
            }
        }
        __syncthreads();
    }
#pragma unroll
    for (int c = 0; c < 16; ++c) {
        int col = c * 16 + l16;
        float bcol = (!SLICEOUT) ? bias[col] : 0.0f;
#pragma unroll
        for (int r = 0; r < 4; ++r) {
            int row = row0 + w * 16 + quad * 4 + r;
            if (row < M) {
                if (SLICEOUT)
                    Cout[((size_t)(c >> 1) * M + row) * 32 + ((c & 1) << 4) + l16] = f2b(acc[c][r]);
                else
                    Cout[(size_t)row * 256 + col] = f2b(acc[c][r] + bcol);
            }
        }
    }
}

// ---------------- aggregation: 4-lane group per slot, slice-major table, LDS edges ------
// Slots degree-sorted (descending): 16 groups per wave see near-equal row lengths.
// slice = blockIdx & mask -> XCD-resident 3.2MB slice. 16 KB LDS edge stage
// (32 KB regressed: occupancy 45->34.6%, dur 77->82.5us — keep 16 KB).
// MLP inner loop kept: per-occupancy throughput was ~18% better than the simple loop.

#define CAPQ 1024   // 4096 edges, 16 KB LDS

template <int CSH>
__global__ __launch_bounds__(256) void agg_grp(
    const unsigned short* __restrict__ tab0, const int* __restrict__ row_ptr,
    const unsigned int* __restrict__ edge, unsigned short* __restrict__ outb, int n) {
    __shared__ uint4v eq[CAPQ];
    int b = blockIdx.x;
    int s = b & ((1 << CSH) - 1);
    int grp = b >> CSH;
    int t = threadIdx.x;
    int d0 = grp * 64;
    int d = d0 + (t >> 2);

    const uint4v* e4p = (const uint4v*)edge;
    int qbase = row_ptr[d0] >> 2;
    int dmax = d0 + 64 < n ? d0 + 64 : n;
    int qcnt = (row_ptr[dmax] >> 2) - qbase;
    int qstage = qcnt < CAPQ ? qcnt : CAPQ;
    for (int i = t; i < qstage; i += 256) eq[i] = NT_LOAD(&e4p[qbase + i]);
    __syncthreads();

    if (d >= n) return;
    int fo = (t & 3) << 3;                    // feature offset within the 32-wide slice
    const unsigned short* tab = tab0 + (size_t)s * n * 32;

    int j = row_ptr[d] >> 2, j1 = row_ptr[d + 1] >> 2;
    int jmid = j1 < qbase + CAPQ ? j1 : qbase + CAPQ;

    float2v a2[4];
#pragma unroll
    for (int k = 0; k < 4; ++k) a2[k] = (float2v){0.f, 0.f};

    // single-edge unpack+fma (used by compute phases and tails)
    auto compq = [&](unsigned e, uint4 r) {
        float wq = __int_as_float((int)(e & 0xffff0000u));
        float2v w2 = {wq, wq};
        float2v f0 = {__uint_as_float(r.x << 16), __uint_as_float(r.x & 0xffff0000u)};
        float2v f1 = {__uint_as_float(r.y << 16), __uint_as_float(r.y & 0xffff0000u)};
        float2v f2 = {__uint_as_float(r.z << 16), __uint_as_float(r.z & 0xffff0000u)};
        float2v f3 = {__uint_as_float(r.w << 16), __uint_as_float(r.w & 0xffff0000u)};
        a2[0] += f0 * w2;
        a2[1] += f1 * w2;
        a2[2] += f2 * w2;
        a2[3] += f3 * w2;
    };
    // combined load+compute for tails (1 quad)
    auto process = [&](uint4v e4) {
#pragma unroll
        for (int u = 0; u < 4; ++u) {
            unsigned e = e4[u];
            unsigned off = ((e & 0xffffu) << 5) + (unsigned)fo;
            uint4 rr = *(const uint4*)(tab + off);
            compq(e, rr);
        }
    };
    // issue phase: 2 quads -> 8 independent 16B loads in flight
    auto issue2 = [&](int jj, uint4v& q0, uint4v& q1, uint4* rr) {
        q0 = eq[jj - qbase];
        q1 = eq[jj + 1 - qbase];
#pragma unroll
        for (int u = 0; u < 4; ++u)
            rr[u] = *(const uint4*)(tab + (((q0[u] & 0xffffu) << 5) + (unsigned)fo));
#pragma unroll
        for (int u = 0; u < 4; ++u)
            rr[4 + u] = *(const uint4*)(tab + (((q1[u] & 0xffffu) << 5) + (unsigned)fo));
    };
    // compute phase: consume 2 quads from registers
    auto comp2 = [&](uint4v q0, uint4v q1, const uint4* rr) {
#pragma unroll
        for (int u = 0; u < 4; ++u) compq(q0[u], rr[u]);
#pragma unroll
        for (int u = 0; u < 4; ++u) compq(q1[u], rr[4 + u]);
    };

    uint4v qA0, qA1, qB0, qB1;
    uint4 rrA[8], rrB[8];
    int nq2 = (jmid - j) >> 1;                // number of 2-quad batches in LDS window
    if (nq2 > 0) {
        issue2(j, qA0, qA1, rrA);
        int bb = 1;
        for (; bb + 1 < nq2; bb += 2) {
            issue2(j + 2 * bb, qB0, qB1, rrB);
            comp2(qA0, qA1, rrA);
            issue2(j + 2 * bb + 2, qA0, qA1, rrA);
            comp2(qB0, qB1, rrB);
        }
        if (bb < nq2) {
            issue2(j + 2 * bb, qB0, qB1, rrB);
            comp2(qA0, qA1, rrA);
            comp2(qB0, qB1, rrB);
        } else {
            comp2(qA0, qA1, rrA);
        }
        j += 2 * nq2;
    }
    if (j < jmid) { process(eq[j - qbase]); ++j; }
    for (; j < j1; ++j) process(NT_LOAD(&e4p[j]));   // overflow fallback (first blocks only)

    ushort8 o;
#pragma unroll
    for (int k = 0; k < 4; ++k) {
        o[2 * k] = f2b(a2[k].x);
        o[2 * k + 1] = f2b(a2[k].y);
    }
    *(ushort8*)(outb + ((size_t)d << (5 + CSH)) + (s << 5) + fo) = o;
}

// ---------------- bias + LayerNorm + residual + ReLU (bf16 in, bf16 out) ----------------

__global__ __launch_bounds__(256) void ln_res_relu(
    const unsigned short* __restrict__ preln, const float* __restrict__ bias,
    const float* __restrict__ g, const float* __restrict__ lb,
    const unsigned short* __restrict__ res, unsigned short* __restrict__ out, int n) {
    int wv = __builtin_amdgcn_readfirstlane(threadIdx.x >> 6);
    int d = blockIdx.x * 4 + wv;
    if (d >= n) return;
    int l = threadIdx.x & 63;
    int fo = l * 4;
    ushort4 pv = *(const ushort4*)&preln[(size_t)d * 256 + fo];
    float4 bb = *(const float4*)&bias[fo];
    float v[4] = {b2f(pv.x) + bb.x, b2f(pv.y) + bb.y, b2f(pv.z) + bb.z, b2f(pv.w) + bb.w};
    float s4 = v[0] + v[1] + v[2] + v[3];
#pragma unroll
    for (int off = 1; off < 64; off <<= 1) s4 += __shfl_xor(s4, off);
    float mu = s4 * (1.0f / 256.0f);
    float dv[4];
    float qs = 0.f;
#pragma unroll
    for (int j = 0; j < 4; ++j) { dv[j] = v[j] - mu; qs += dv[j] * dv[j]; }
#pragma unroll
    for (int off = 1; off < 64; off <<= 1) qs += __shfl_xor(qs, off);
    float rs = rsqrtf(qs * (1.0f / 256.0f) + EPS);

    float4 gg = *(const float4*)&g[fo];
    float4 lbv = *(const float4*)&lb[fo];
    ushort4 rr4 = *(const ushort4*)&res[(size_t)d * 256 + fo];
    float ggv[4] = {gg.x, gg.y, gg.z, gg.w};
    float lbvv[4] = {lbv.x, lbv.y, lbv.z, lbv.w};
    float rrv[4] = {b2f(rr4.x), b2f(rr4.y), b2f(rr4.z), b2f(rr4.w)};
    ushort4 o;
    unsigned short* op = (unsigned short*)&o;
#pragma unroll
    for (int j = 0; j < 4; ++j) {
        float x = dv[j] * rs * ggv[j] + lbvv[j] + rrv[j];
        op[j] = f2b(x > 0.f ? x : 0.f);
    }
    *(ushort4*)&out[(size_t)d * 256 + fo] = o;
}

// ---------------- head ----------------

__global__ __launch_bounds__(256) void colsum_kernel(const unsigned short* __restrict__ x,
                                                     float* __restrict__ sums, int n) {
    int h = threadIdx.x;
    float acc = 0.0f;
    for (int r = blockIdx.x; r < n; r += gridDim.x) acc += b2f(x[(size_t)r * 256 + h]);
    atomicAdd(&sums[h], acc);
}

__global__ __launch_bounds__(64) void final_kernel(const float* __restrict__ sums,
                                                   const float* __restrict__ fcW,
                                                   const float* __restrict__ fcb,
                                                   float* __restrict__ out, float invN) {
    int lane = threadIdx.x;
    float p0 = 0.0f, p1 = 0.0f;
    for (int hh = lane; hh < 256; hh += 64) {
        float m = sums[hh];
        p0 += m * fcW[hh * 2 + 0];
        p1 += m * fcW[hh * 2 + 1];
    }
    for (int off = 32; off > 0; off >>= 1) {
        p0 += __shfl_down(p0, off);
        p1 += __shfl_down(p1, off);
    }
    if (lane == 0) {
        out[0] = p0 * invN + fcb[0];
        out[1] = p1 * invN + fcb[1];
    }
}

// ---------------- launch ----------------

extern "C" void kernel_launch(void* const* d_in, const int* in_sizes, int n_in,
                              void* d_out, int out_size, void* d_ws, size_t ws_size,
                              hipStream_t stream) {
    const float* node    = (const float*)d_in[0];
    const int*   edges   = (const int*)d_in[1];
    const float* eattr   = (const float*)d_in[2];
    const float* W1      = (const float*)d_in[3];
    const float* b1      = (const float*)d_in[4];
    const float* W_convs = (const float*)d_in[5];
    const float* b_convs = (const float*)d_in[6];
    const float* ln_g    = (const float*)d_in[7];
    const float* ln_b    = (const float*)d_in[8];
    const float* fc_W    = (const float*)d_in[9];
    const float* fc_b    = (const float*)d_in[10];
    float* out = (float*)d_out;

    const int H = in_sizes[4];           // 256
    const int F = in_sizes[3] / H;       // 128
    const int N = in_sizes[0] / F;       // 50000
    const int E = in_sizes[2];           // 1600000
    const int L = in_sizes[6] / H;       // 3

    const int* src = edges;
    const int* dst = edges + E;

    char* p = (char*)d_ws;
    auto alloc = [&](size_t bytes) {
        char* r = p;
        p += (bytes + 255) & ~(size_t)255;
        return r;
    };
    int nblk = (N + 255) / 256;
    int nb1024 = (N + 1023) / 1024;
    // zeroed region: padded combo (64B/node) + colsums, contiguous
    unsigned long long* combo = (unsigned long long*)alloc((size_t)N * 64);
    float* colsums = (float*)alloc((size_t)H * 4);
    size_t zero_bytes = (size_t)((char*)colsums - (char*)combo) + (((size_t)H * 4 + 255) & ~(size_t)255);
    int*   blockhist = (int*)alloc((size_t)nblk * NBK * 4);
    int*   blockpre  = (int*)alloc((size_t)nblk * NBK * 4);
    int*   tot       = (int*)alloc((size_t)NBK * 4);
    int*   bbase     = (int*)alloc((size_t)NBK * 4);
    int*   perm    = (int*)alloc((size_t)N * 4);
    int*   posod   = (int*)alloc((size_t)N * 4);
    int*   qlen    = (int*)alloc((size_t)N * 4);
    float* dinv    = (float*)alloc((size_t)N * 4);
    int*   row_ptr = (int*)alloc((size_t)(N + 1) * 4);
    int*   bsum    = (int*)alloc((size_t)nb1024 * 4);
    unsigned int* edge = (unsigned int*)alloc(((size_t)E + 4 * (size_t)N + 64) * 4);
    unsigned short* Wt1 = (unsigned short*)alloc((size_t)H * F * 2);
    unsigned short* Wtc = (unsigned short*)alloc((size_t)L * H * H * 2);
    unsigned short* xw  = (unsigned short*)alloc((size_t)N * H * 2);   // sliced [8][N][32]
    unsigned short* preln = (unsigned short*)alloc((size_t)N * H * 2); // row-major [N][256]
    unsigned short* bufA  = (unsigned short*)alloc((size_t)N * H * 2); // bf16 x
    unsigned short* bufB  = (unsigned short*)alloc((size_t)N * H * 2); // bf16 x
    // aliases (dead before their slabs' first real use):
    int*            rank  = (int*)xw;                     // E*4 <= N*H*2
    unsigned short* nodeb = preln;                        // sliced [4][N][32] = N*128 shorts
    unsigned short* aggn  = preln + (size_t)N * F;        // bf16 [N][128] row-major

    hipMemsetAsync(combo, 0, zero_bytes, stream);

    int gE = (E + 255) / 256;
    rank_kernel<<<gE, 256, 0, stream>>>(dst, eattr, combo, rank, E);
    dinv_kernel<<<nblk, 256, 0, stream>>>(combo, dinv, N);
    bin_hist_kernel<<<nblk, 256, 0, stream>>>(combo, blockhist, N);
    bin_prescan_kernel<<<NBK, 256, 0, stream>>>(blockhist, blockpre, tot, nblk);
    bin_suffix_kernel<<<1, 64, 0, stream>>>(tot, bbase);
    bin_scatter_kernel<<<nblk, 256, 0, stream>>>(combo, bbase, blockpre, perm, posod, qlen, N);
    scan_local_kernel<<<nb1024, 1024, 0, stream>>>(qlen, row_ptr, bsum, N);
    scan_mid_kernel<<<1, 64, 0, stream>>>(bsum, row_ptr, nb1024);
    scan_add_kernel<<<nb1024, 1024, 0, stream>>>(bsum, row_ptr, N);
    selfpad_kernel<<<nblk, 256, 0, stream>>>(combo, row_ptr, posod, dinv, edge, N);
    scatter2_kernel<<<gE, 256, 0, stream>>>(src, dst, eattr, rank, row_ptr, posod, dinv, edge, E);

    cast_sliced_kernel<<<(N * (F / 4) + 255) / 256, 256, 0, stream>>>(node, perm, nodeb, N, F);
    wtrans_kernel<<<(F * H + 255) / 256, 256, 0, stream>>>(W1, Wt1, F, H);
    for (int i = 0; i < L; ++i)
        wtrans_kernel<<<(H * H + 255) / 256, 256, 0, stream>>>(
            W_convs + (size_t)i * H * H, Wtc + (size_t)i * H * H, H, H);

    int ngrp64 = (N + 63) / 64;
    int lngrid = (N + 3) / 4;
    int ggrid = (N + 63) / 64;

    // layer 1 (slot space): aggn = agg(node); x1 = aggn @ W1 + b1 (bf16)
    agg_grp<2><<<4 * ngrp64, 256, 0, stream>>>(nodeb, row_ptr, edge, aggn, N);
    gemm_n256<false><<<ggrid, 256, 0, stream>>>(aggn, Wt1, bufA, b1, N, F);

    unsigned short* x = bufA;
    unsigned short* other = bufB;
    for (int i = 0; i < L; ++i) {
        gemm_n256<true><<<ggrid, 256, 0, stream>>>(x, Wtc + (size_t)i * H * H, xw, nullptr, N, H);
        agg_grp<3><<<8 * ngrp64, 256, 0, stream>>>(xw, row_ptr, edge, preln, N);
        ln_res_relu<<<lngrid, 256, 0, stream>>>(preln, b_convs + (size_t)i * H,
                                                ln_g + (size_t)i * H, ln_b + (size_t)i * H,
                                                x, other, N);
        unsigned short* t = x; x = other; other = t;
    }

    colsum_kernel<<<256, 256, 0, stream>>>(x, colsums, N);
    final_kernel<<<1, 64, 0, stream>>>(colsums, fc_W, fc_b, out, 1.0f / (float)N);
}

// Round 5
// 693.532 us; speedup vs baseline: 1.0788x; 1.0278x over previous
//
#include <hip/hip_runtime.h>

#define EPS 1e-5f
#define FIXSCALE 8388608.0f   // 2^23 fixed-point for degree accumulation
#define NBK 64                // degree buckets (qc clamped)

typedef __attribute__((ext_vector_type(8))) short short8;
typedef __attribute__((ext_vector_type(4))) short short4v;
typedef __attribute__((ext_vector_type(4))) float float4v;
typedef __attribute__((ext_vector_type(2))) float float2v;
typedef __attribute__((ext_vector_type(8))) unsigned short ushort8;
typedef __attribute__((ext_vector_type(4))) unsigned int uint4v;

#if __has_builtin(__builtin_nontemporal_load)
#define NT_LOAD(p) __builtin_nontemporal_load(p)
#else
#define NT_LOAD(p) (*(p))
#endif

__device__ __forceinline__ unsigned short f2b(float f) {
    union { float f; unsigned u; } v; v.f = f;
    unsigned r = v.u + 0x7FFF + ((v.u >> 16) & 1);   // RNE
    return (unsigned short)(r >> 16);
}
__device__ __forceinline__ float b2f(unsigned short u) {
    union { unsigned u; float f; } v; v.u = ((unsigned)u) << 16;
    return v.f;
}

__device__ __forceinline__ int qbucket(int cnt) {
    int qc = ((cnt + 4) & ~3) >> 2;
    return qc < NBK - 1 ? qc : NBK - 1;
}

// ---------------- setup kernels ----------------

// ONE atomic per edge; combo padded to 1 node / 64B line
__global__ __launch_bounds__(256) void rank_kernel(const int* __restrict__ dst,
                                                   const float* __restrict__ w,
                                                   unsigned long long* __restrict__ combo,
                                                   int* __restrict__ rank, int E) {
    int e = blockIdx.x * 256 + threadIdx.x;
    if (e < E) {
        int d = dst[e];
        unsigned long long pack = (1ULL << 32) | (unsigned long long)(unsigned)(w[e] * FIXSCALE);
        unsigned long long old = atomicAdd(&combo[(size_t)d * 8], pack);
        rank[e] = (int)(old >> 32);
    }
}

// fused: dinv per original node + per-block degree histogram (one combo read)
__global__ __launch_bounds__(256) void dinv_hist_kernel(const unsigned long long* __restrict__ combo,
                                                        float* __restrict__ dinv,
                                                        int* __restrict__ blockhist, int n) {
    __shared__ int lh[NBK];
    int t = threadIdx.x;
    if (t < NBK) lh[t] = 0;
    __syncthreads();
    int d = blockIdx.x * 256 + t;
    if (d < n) {
        unsigned long long cw = combo[(size_t)d * 8];
        int cnt = (int)(cw >> 32);
        float degv = (float)(unsigned)(cw & 0xffffffffULL) * (1.0f / FIXSCALE);
        dinv[d] = rsqrtf(degv + 1.0f);
        atomicAdd(&lh[qbucket(cnt)], 1);
    }
    __syncthreads();
    if (t < NBK) blockhist[blockIdx.x * NBK + t] = lh[t];
}

// one block PER BUCKET: exclusive prefix of its per-block counts + bucket total
__global__ __launch_bounds__(256) void bin_prescan_kernel(const int* __restrict__ blockhist,
                                                          int* __restrict__ blockpre,
                                                          int* __restrict__ tot, int nblk) {
    int bkt = blockIdx.x;
    int t = threadIdx.x, lane = t & 63, w = t >> 6;
    __shared__ int wsum[4];
    __shared__ int s_carry;
    if (t == 0) s_carry = 0;
    __syncthreads();
    for (int base = 0; base < nblk; base += 256) {
        int i = base + t;
        int v = (i < nblk) ? blockhist[i * NBK + bkt] : 0;
        int x = v;
        for (int off = 1; off < 64; off <<= 1) {
            int u = __shfl_up(x, off);
            if (lane >= off) x += u;
        }
        if (lane == 63) wsum[w] = x;
        __syncthreads();
        if (t == 0) {
            int a = wsum[0];
            wsum[0] = 0;
            for (int k = 1; k < 4; ++k) { int b = wsum[k]; wsum[k] = a; a += b; }
            wsum[0] = 0;
        }
        __syncthreads();
        int carry = s_carry;
        int woff = wsum[w];
        if (i < nblk) blockpre[i * NBK + bkt] = carry + woff + x - v;
        __syncthreads();
        if (t == 255) s_carry = carry + woff + x;
        __syncthreads();
    }
    if (t == 0) tot[bkt] = s_carry;
}

// single wave: base[b] = sum_{b' > b} tot[b']  (descending buckets first)
__global__ __launch_bounds__(64) void bin_suffix_kernel(const int* __restrict__ tot,
                                                        int* __restrict__ base) {
    int t = threadIdx.x;
    int v = tot[t];
    int s = v;
    for (int off = 1; off < 64; off <<= 1) {
        int u = __shfl_down(s, off);
        if (t + off < 64) s += u;
    }
    base[t] = s - v;
}

// assign slots via LDS cursors; also record each slot's padded quad length (linear later)
__global__ __launch_bounds__(256) void bin_scatter_kernel(const unsigned long long* __restrict__ combo,
                                                          const int* __restrict__ base,
                                                          const int* __restrict__ blockpre,
                                                          int* __restrict__ perm,
                                                          int* __restrict__ posod,
                                                          int* __restrict__ qlen, int n) {
    __shared__ int lcur[NBK];
    int t = threadIdx.x;
    if (t < NBK) lcur[t] = base[t] + blockpre[blockIdx.x * NBK + t];
    __syncthreads();
    int d = blockIdx.x * 256 + t;
    if (d < n) {
        int cnt = (int)(combo[(size_t)d * 8] >> 32);
        int pos = atomicAdd(&lcur[qbucket(cnt)], 1);
        perm[pos] = d;
        posod[d] = pos;
        qlen[pos] = (cnt + 4) & ~3;
    }
}

// ---- row_ptr over permuted slots: 3-kernel multi-block scan ----

// block-local inclusive scan of qlen -> row_ptr[i+1]; block totals -> bsum
__global__ __launch_bounds__(1024) void scan_local_kernel(const int* __restrict__ qlen,
                                                          int* __restrict__ row_ptr,
                                                          int* __restrict__ bsum, int n) {
    int tid = threadIdx.x, lane = tid & 63, w = tid >> 6;
    __shared__ int wsum[16];
    int i = blockIdx.x * 1024 + tid;
    int v = (i < n) ? qlen[i] : 0;
    int x = v;
    for (int off = 1; off < 64; off <<= 1) {
        int t = __shfl_up(x, off);
        if (lane >= off) x += t;
    }
    if (lane == 63) wsum[w] = x;
    __syncthreads();
    if (w == 0 && lane < 16) {
        int s = wsum[lane];
        for (int off = 1; off < 16; off <<= 1) {
            int t = __shfl_up(s, off, 16);
            if (lane >= off) s += t;
        }
        wsum[lane] = s;
    }
    __syncthreads();
    int woff = (w > 0) ? wsum[w - 1] : 0;
    if (i < n) row_ptr[i + 1] = woff + x;
    if (tid == 0) bsum[blockIdx.x] = wsum[15];
}

// single wave: exclusive scan of block sums (carry loop handles nb > 64); row_ptr[0] = 0
__global__ __launch_bounds__(64) void scan_mid_kernel(int* __restrict__ bsum,
                                                      int* __restrict__ row_ptr, int nb) {
    int t = threadIdx.x;
    int carry = 0;
    for (int base = 0; base < nb; base += 64) {
        int idx = base + t;
        int v = (idx < nb) ? bsum[idx] : 0;
        int x = v;
        for (int off = 1; off < 64; off <<= 1) {
            int u = __shfl_up(x, off);
            if (t >= off) x += u;
        }
        if (idx < nb) bsum[idx] = carry + x - v;
        carry += __shfl(x, 63);
    }
    if (t == 0) row_ptr[0] = 0;
}

// add block offsets
__global__ __launch_bounds__(1024) void scan_add_kernel(const int* __restrict__ bsum,
                                                        int* __restrict__ row_ptr, int n) {
    int i = blockIdx.x * 1024 + threadIdx.x;
    if (i < n) row_ptr[i + 1] += bsum[blockIdx.x];
}

// self-edge (slot 0, weight dinv^2, src = own slot) + zero-weight pads
__global__ __launch_bounds__(256) void selfpad_kernel(const unsigned long long* __restrict__ combo,
                                                      const int* __restrict__ row_ptr,
                                                      const int* __restrict__ posod,
                                                      const float* __restrict__ dinv,
                                                      unsigned int* __restrict__ edge, int n) {
    int d = blockIdx.x * 256 + threadIdx.x;
    if (d < n) {
        int cnt = (int)(combo[(size_t)d * 8] >> 32);
        int slot = posod[d];
        int j0 = row_ptr[slot], j1 = row_ptr[slot + 1];
        float di = dinv[d];
        edge[j0] = ((unsigned)f2b(di * di) << 16) | (unsigned)slot;
        for (int j = j0 + 1 + cnt; j < j1; ++j) edge[j] = (unsigned)slot;  // w = +0
    }
}

// atomic-free scatter into permuted CSR; record = wn(bf16)<<16 | srcslot(u16)
__global__ __launch_bounds__(256) void scatter2_kernel(
    const int* __restrict__ src, const int* __restrict__ dst,
    const float* __restrict__ w, const int* __restrict__ rank,
    const int* __restrict__ row_ptr, const int* __restrict__ posod,
    const float* __restrict__ dinv, unsigned int* __restrict__ edge, int E) {
    int e = blockIdx.x * 256 + threadIdx.x;
    if (e < E) {
        int d = dst[e], s = src[e];
        float wn = dinv[s] * w[e] * dinv[d];
        edge[row_ptr[posod[d]] + 1 + rank[e]] = ((unsigned)f2b(wn) << 16) | (unsigned)posod[s];
    }
}

// node f32 [N][F] (original order) -> bf16 slice-major [F/32][n][32] in SLOT order
__global__ __launch_bounds__(256) void cast_sliced_kernel(const float* __restrict__ in,
                                                          const int* __restrict__ perm,
                                                          unsigned short* __restrict__ out,
                                                          int n, int F) {
    int idx = blockIdx.x * 256 + threadIdx.x;
    if (idx < n * (F / 4)) {
        int f4 = idx * 4;
        int slot = f4 / F, f = f4 - slot * F;
        float4 v = *(const float4*)&in[(size_t)perm[slot] * F + f];
        short4v s = (short4v){(short)f2b(v.x), (short)f2b(v.y), (short)f2b(v.z), (short)f2b(v.w)};
        *(short4v*)&out[((size_t)(f >> 5) * n + slot) * 32 + (f & 31)] = s;
    }
}

// batched transpose+cast: Wt[l][n][k] = W[l][k][n], l in [0,nl)
__global__ __launch_bounds__(256) void wtransL_kernel(const float* __restrict__ W,
                                                      unsigned short* __restrict__ Wt,
                                                      int K, int Nc, int total) {
    int o = blockIdx.x * 256 + threadIdx.x;
    if (o < total) {
        int l = o / (K * Nc);
        int r = o - l * K * Nc;
        int n = r / K, k = r - n * K;
        Wt[o] = f2b(W[(size_t)l * K * Nc + (size_t)k * Nc + n]);
    }
}

// ---------------- bf16 MFMA GEMM, full-N strip: C[M,256] = A[M,K](bf16) @ Bt[256,K]^T ----

#define GST 88

template <bool SLICEOUT>
__global__ __launch_bounds__(256) void gemm_n256(const unsigned short* __restrict__ A,
                                                 const unsigned short* __restrict__ Bt,
                                                 unsigned short* __restrict__ Cout,
                                                 const float* __restrict__ bias,
                                                 int M, int K) {
    __shared__ __align__(16) short As[64 * GST];
    __shared__ __align__(16) short Bs[256 * GST];
    int t = threadIdx.x;
    int lane = t & 63, w = t >> 6;
    int quad = lane >> 4, l16 = lane & 15;
    int row0 = blockIdx.x * 64;

    float4v acc[16];
#pragma unroll
    for (int c = 0; c < 16; ++c) acc[c] = (float4v){0.f, 0.f, 0.f, 0.f};

    int arow = t >> 2, ak16 = (t & 3) * 16;
    int bcol0 = t >> 2, bko = (t & 3) * 16;

    for (int k_outer = 0; k_outer < K; k_outer += 64) {
        bool rowok = (row0 + arow) < M;
        const unsigned short* ap = &A[(size_t)(row0 + arow) * K + k_outer + ak16];
        uint4 z = make_uint4(0, 0, 0, 0);
        uint4 u0 = rowok ? *(const uint4*)ap : z;
        uint4 u1 = rowok ? *(const uint4*)(ap + 8) : z;
        *(uint4*)&As[arow * GST + ak16] = u0;
        *(uint4*)&As[arow * GST + ak16 + 8] = u1;
#pragma unroll
        for (int cb = 0; cb < 4; ++cb) {
            int col = bcol0 + 64 * cb;
            const unsigned short* bp = &Bt[(size_t)col * K + k_outer + bko];
#pragma unroll
            for (int u = 0; u < 2; ++u)
                *(uint4*)&Bs[col * GST + bko + u * 8] = *(const uint4*)&bp[u * 8];
        }
        __syncthreads();
#pragma unroll
        for (int k0 = 0; k0 < 64; k0 += 32) {
            short8 a = *(const short8*)&As[(w * 16 + l16) * GST + k0 + quad * 8];
#pragma unroll
            for (int c = 0; c < 16; ++c) {
                short8 b = *(const short8*)&Bs[(c * 16 + l16) * GST + k0 + quad * 8];
                acc[c] = __builtin_amdgcn_mfma_f32_16x16x32_bf16(a, b, acc[c], 0, 0, 0);
            }
        }
        __syncthreads();
    }
#pragma unroll
    for (int c = 0; c < 16; ++c) {
        int col = c * 16 + l16;
        float bcol = (!SLICEOUT) ? bias[col] : 0.0f;
#pragma unroll
        for (int r = 0; r < 4; ++r) {
            int row = row0 + w * 16 + quad * 4 + r;
            if (row < M) {
                if (SLICEOUT)
                    Cout[((size_t)(c >> 1) * M + row) * 32 + ((c & 1) << 4) + l16] = f2b(acc[c][r]);
                else
                    Cout[(size_t)row * 256 + col] = f2b(acc[c][r] + bcol);
            }
        }
    }
}

// ---------------- aggregation: 4-lane group per slot, slice-major table, LDS edges ------
// Slots degree-sorted (descending): 16 groups per wave see near-equal row lengths.
// slice = blockIdx & mask -> XCD-resident 3.2MB slice. 16 KB LDS edge stage.
//
// NOTE (r2/r4 evidence): gather rate ~10.6-11.5 TB/s from L2 is invariant to
// occupancy (35-45%) and inner-loop MLP restructuring -> L2-side random-64B
// service cap (~9 lines/cy/XCD). Bytes gathered (E_pad x 512B bf16) are the
// algorithmic minimum. Simple loop is fastest (77.4us); keep it.

#define CAPQ 1024   // 4096 edges, 16 KB LDS

template <int CSH>
__global__ __launch_bounds__(256) void agg_grp(
    const unsigned short* __restrict__ tab0, const int* __restrict__ row_ptr,
    const unsigned int* __restrict__ edge, unsigned short* __restrict__ outb, int n) {
    __shared__ uint4v eq[CAPQ];
    int b = blockIdx.x;
    int s = b & ((1 << CSH) - 1);
    int grp = b >> CSH;
    int t = threadIdx.x;
    int d0 = grp * 64;
    int d = d0 + (t >> 2);

    const uint4v* e4p = (const uint4v*)edge;
    int qbase = row_ptr[d0] >> 2;
    int dmax = d0 + 64 < n ? d0 + 64 : n;
    int qcnt = (row_ptr[dmax] >> 2) - qbase;
    int qstage = qcnt < CAPQ ? qcnt : CAPQ;
    for (int i = t; i < qstage; i += 256) eq[i] = NT_LOAD(&e4p[qbase + i]);
    __syncthreads();

    if (d >= n) return;
    int fo = (t & 3) << 3;                    // feature offset within the 32-wide slice
    const unsigned short* tab = tab0 + (size_t)s * n * 32;

    int j = row_ptr[d] >> 2, j1 = row_ptr[d + 1] >> 2;
    int jmid = j1 < qbase + CAPQ ? j1 : qbase + CAPQ;

    float2v a2[4];
#pragma unroll
    for (int k = 0; k < 4; ++k) a2[k] = (float2v){0.f, 0.f};

    auto process = [&](uint4v e4) {
#pragma unroll
        for (int u = 0; u < 4; ++u) {
            unsigned e = e4[u];
            float wq = __int_as_float((int)(e & 0xffff0000u));
            float2v w2 = {wq, wq};
            unsigned off = ((e & 0xffffu) << 5) + (unsigned)fo;
            uint4 rr = *(const uint4*)(tab + off);
            unsigned uu0 = rr.x, uu1 = rr.y, uu2 = rr.z, uu3 = rr.w;
            float2v f0 = {__uint_as_float(uu0 << 16), __uint_as_float(uu0 & 0xffff0000u)};
            float2v f1 = {__uint_as_float(uu1 << 16), __uint_as_float(uu1 & 0xffff0000u)};
            float2v f2 = {__uint_as_float(uu2 << 16), __uint_as_float(uu2 & 0xffff0000u)};
            float2v f3 = {__uint_as_float(uu3 << 16), __uint_as_float(uu3 & 0xffff0000u)};
            a2[0] += f0 * w2;
            a2[1] += f1 * w2;
            a2[2] += f2 * w2;
            a2[3] += f3 * w2;
        }
    };

    for (; j + 2 <= jmid; j += 2) {
        uint4v e4a = eq[j - qbase];
        uint4v e4b = eq[j + 1 - qbase];
        process(e4a);
        process(e4b);
    }
    if (j < jmid) { process(eq[j - qbase]); ++j; }
    for (; j < j1; ++j) process(NT_LOAD(&e4p[j]));   // overflow fallback (first blocks only)

    ushort8 o;
#pragma unroll
    for (int k = 0; k < 4; ++k) {
        o[2 * k] = f2b(a2[k].x);
        o[2 * k + 1] = f2b(a2[k].y);
    }
    *(ushort8*)(outb + ((size_t)d << (5 + CSH)) + (s << 5) + fo) = o;
}

// ---------------- bias + LayerNorm + residual + ReLU (bf16 in, bf16 out) ----------------

__global__ __launch_bounds__(256) void ln_res_relu(
    const unsigned short* __restrict__ preln, const float* __restrict__ bias,
    const float* __restrict__ g, const float* __restrict__ lb,
    const unsigned short* __restrict__ res, unsigned short* __restrict__ out, int n) {
    int wv = __builtin_amdgcn_readfirstlane(threadIdx.x >> 6);
    int d = blockIdx.x * 4 + wv;
    if (d >= n) return;
    int l = threadIdx.x & 63;
    int fo = l * 4;
    ushort4 pv = *(const ushort4*)&preln[(size_t)d * 256 + fo];
    float4 bb = *(const float4*)&bias[fo];
    float v[4] = {b2f(pv.x) + bb.x, b2f(pv.y) + bb.y, b2f(pv.z) + bb.z, b2f(pv.w) + bb.w};
    float s4 = v[0] + v[1] + v[2] + v[3];
#pragma unroll
    for (int off = 1; off < 64; off <<= 1) s4 += __shfl_xor(s4, off);
    float mu = s4 * (1.0f / 256.0f);
    float dv[4];
    float qs = 0.f;
#pragma unroll
    for (int j = 0; j < 4; ++j) { dv[j] = v[j] - mu; qs += dv[j] * dv[j]; }
#pragma unroll
    for (int off = 1; off < 64; off <<= 1) qs += __shfl_xor(qs, off);
    float rs = rsqrtf(qs * (1.0f / 256.0f) + EPS);

    float4 gg = *(const float4*)&g[fo];
    float4 lbv = *(const float4*)&lb[fo];
    ushort4 rr4 = *(const ushort4*)&res[(size_t)d * 256 + fo];
    float ggv[4] = {gg.x, gg.y, gg.z, gg.w};
    float lbvv[4] = {lbv.x, lbv.y, lbv.z, lbv.w};
    float rrv[4] = {b2f(rr4.x), b2f(rr4.y), b2f(rr4.z), b2f(rr4.w)};
    ushort4 o;
    unsigned short* op = (unsigned short*)&o;
#pragma unroll
    for (int j = 0; j < 4; ++j) {
        float x = dv[j] * rs * ggv[j] + lbvv[j] + rrv[j];
        op[j] = f2b(x > 0.f ? x : 0.f);
    }
    *(ushort4*)&out[(size_t)d * 256 + fo] = o;
}

// ---------------- head ----------------

__global__ __launch_bounds__(256) void colsum_kernel(const unsigned short* __restrict__ x,
                                                     float* __restrict__ sums, int n) {
    int h = threadIdx.x;
    float acc = 0.0f;
    for (int r = blockIdx.x; r < n; r += gridDim.x) acc += b2f(x[(size_t)r * 256 + h]);
    atomicAdd(&sums[h], acc);
}

__global__ __launch_bounds__(64) void final_kernel(const float* __restrict__ sums,
                                                   const float* __restrict__ fcW,
                                                   const float* __restrict__ fcb,
                                                   float* __restrict__ out, float invN) {
    int lane = threadIdx.x;
    float p0 = 0.0f, p1 = 0.0f;
    for (int hh = lane; hh < 256; hh += 64) {
        float m = sums[hh];
        p0 += m * fcW[hh * 2 + 0];
        p1 += m * fcW[hh * 2 + 1];
    }
    for (int off = 32; off > 0; off >>= 1) {
        p0 += __shfl_down(p0, off);
        p1 += __shfl_down(p1, off);
    }
    if (lane == 0) {
        out[0] = p0 * invN + fcb[0];
        out[1] = p1 * invN + fcb[1];
    }
}

// ---------------- launch ----------------

extern "C" void kernel_launch(void* const* d_in, const int* in_sizes, int n_in,
                              void* d_out, int out_size, void* d_ws, size_t ws_size,
                              hipStream_t stream) {
    const float* node    = (const float*)d_in[0];
    const int*   edges   = (const int*)d_in[1];
    const float* eattr   = (const float*)d_in[2];
    const float* W1      = (const float*)d_in[3];
    const float* b1      = (const float*)d_in[4];
    const float* W_convs = (const float*)d_in[5];
    const float* b_convs = (const float*)d_in[6];
    const float* ln_g    = (const float*)d_in[7];
    const float* ln_b    = (const float*)d_in[8];
    const float* fc_W    = (const float*)d_in[9];
    const float* fc_b    = (const float*)d_in[10];
    float* out = (float*)d_out;

    const int H = in_sizes[4];           // 256
    const int F = in_sizes[3] / H;       // 128
    const int N = in_sizes[0] / F;       // 50000
    const int E = in_sizes[2];           // 1600000
    const int L = in_sizes[6] / H;       // 3

    const int* src = edges;
    const int* dst = edges + E;

    char* p = (char*)d_ws;
    auto alloc = [&](size_t bytes) {
        char* r = p;
        p += (bytes + 255) & ~(size_t)255;
        return r;
    };
    int nblk = (N + 255) / 256;
    int nb1024 = (N + 1023) / 1024;
    // zeroed region: padded combo (64B/node) + colsums, contiguous
    unsigned long long* combo = (unsigned long long*)alloc((size_t)N * 64);
    float* colsums = (float*)alloc((size_t)H * 4);
    size_t zero_bytes = (size_t)((char*)colsums - (char*)combo) + (((size_t)H * 4 + 255) & ~(size_t)255);
    int*   blockhist = (int*)alloc((size_t)nblk * NBK * 4);
    int*   blockpre  = (int*)alloc((size_t)nblk * NBK * 4);
    int*   tot       = (int*)alloc((size_t)NBK * 4);
    int*   bbase     = (int*)alloc((size_t)NBK * 4);
    int*   perm    = (int*)alloc((size_t)N * 4);
    int*   posod   = (int*)alloc((size_t)N * 4);
    int*   qlen    = (int*)alloc((size_t)N * 4);
    float* dinv    = (float*)alloc((size_t)N * 4);
    int*   row_ptr = (int*)alloc((size_t)(N + 1) * 4);
    int*   bsum    = (int*)alloc((size_t)nb1024 * 4);
    unsigned int* edge = (unsigned int*)alloc(((size_t)E + 4 * (size_t)N + 64) * 4);
    unsigned short* Wt1 = (unsigned short*)alloc((size_t)H * F * 2);
    unsigned short* Wtc = (unsigned short*)alloc((size_t)L * H * H * 2);
    unsigned short* xw  = (unsigned short*)alloc((size_t)N * H * 2);   // sliced [8][N][32]
    unsigned short* preln = (unsigned short*)alloc((size_t)N * H * 2); // row-major [N][256]
    unsigned short* bufA  = (unsigned short*)alloc((size_t)N * H * 2); // bf16 x
    unsigned short* bufB  = (unsigned short*)alloc((size_t)N * H * 2); // bf16 x
    // aliases (dead before their slabs' first real use):
    int*            rank  = (int*)xw;                     // E*4 <= N*H*2
    unsigned short* nodeb = preln;                        // sliced [4][N][32] = N*128 shorts
    unsigned short* aggn  = preln + (size_t)N * F;        // bf16 [N][128] row-major

    hipMemsetAsync(combo, 0, zero_bytes, stream);

    int gE = (E + 255) / 256;
    rank_kernel<<<gE, 256, 0, stream>>>(dst, eattr, combo, rank, E);
    dinv_hist_kernel<<<nblk, 256, 0, stream>>>(combo, dinv, blockhist, N);
    bin_prescan_kernel<<<NBK, 256, 0, stream>>>(blockhist, blockpre, tot, nblk);
    bin_suffix_kernel<<<1, 64, 0, stream>>>(tot, bbase);
    bin_scatter_kernel<<<nblk, 256, 0, stream>>>(combo, bbase, blockpre, perm, posod, qlen, N);
    scan_local_kernel<<<nb1024, 1024, 0, stream>>>(qlen, row_ptr, bsum, N);
    scan_mid_kernel<<<1, 64, 0, stream>>>(bsum, row_ptr, nb1024);
    scan_add_kernel<<<nb1024, 1024, 0, stream>>>(bsum, row_ptr, N);
    selfpad_kernel<<<nblk, 256, 0, stream>>>(combo, row_ptr, posod, dinv, edge, N);
    scatter2_kernel<<<gE, 256, 0, stream>>>(src, dst, eattr, rank, row_ptr, posod, dinv, edge, E);

    cast_sliced_kernel<<<(N * (F / 4) + 255) / 256, 256, 0, stream>>>(node, perm, nodeb, N, F);
    wtransL_kernel<<<(F * H + 255) / 256, 256, 0, stream>>>(W1, Wt1, F, H, F * H);
    wtransL_kernel<<<(L * H * H + 255) / 256, 256, 0, stream>>>(W_convs, Wtc, H, H, L * H * H);

    int ngrp64 = (N + 63) / 64;
    int lngrid = (N + 3) / 4;
    int ggrid = (N + 63) / 64;

    // layer 1 (slot space): aggn = agg(node); x1 = aggn @ W1 + b1 (bf16)
    agg_grp<2><<<4 * ngrp64, 256, 0, stream>>>(nodeb, row_ptr, edge, aggn, N);
    gemm_n256<false><<<ggrid, 256, 0, stream>>>(aggn, Wt1, bufA, b1, N, F);

    unsigned short* x = bufA;
    unsigned short* other = bufB;
    for (int i = 0; i < L; ++i) {
        gemm_n256<true><<<ggrid, 256, 0, stream>>>(x, Wtc + (size_t)i * H * H, xw, nullptr, N, H);
        agg_grp<3><<<8 * ngrp64, 256, 0, stream>>>(xw, row_ptr, edge, preln, N);
        ln_res_relu<<<lngrid, 256, 0, stream>>>(preln, b_convs + (size_t)i * H,
                                                ln_g + (size_t)i * H, ln_b + (size_t)i * H,
                                                x, other, N);
        unsigned short* t = x; x = other; other = t;
    }

    colsum_kernel<<<256, 256, 0, stream>>>(x, colsums, N);
    final_kernel<<<1, 64, 0, stream>>>(colsums, fc_W, fc_b, out, 1.0f / (float)N);
}

// Round 7
// 683.015 us; speedup vs baseline: 1.0955x; 1.0154x over previous
//
#include <hip/hip_runtime.h>

#define EPS 1e-5f
#define WSCALE 65536.0f       // 2^16 fixed-point for degree accumulation (24-bit field)
#define NBK 64                // degree buckets (qc clamped)

typedef __attribute__((ext_vector_type(8))) short short8;
typedef __attribute__((ext_vector_type(4))) short short4v;
typedef __attribute__((ext_vector_type(4))) float float4v;
typedef __attribute__((ext_vector_type(2))) float float2v;
typedef __attribute__((ext_vector_type(8))) unsigned short ushort8;
typedef __attribute__((ext_vector_type(4))) unsigned int uint4v;

#if __has_builtin(__builtin_nontemporal_load)
#define NT_LOAD(p) __builtin_nontemporal_load(p)
#else
#define NT_LOAD(p) (*(p))
#endif

__device__ __forceinline__ unsigned short f2b(float f) {
    union { float f; unsigned u; } v; v.f = f;
    unsigned r = v.u + 0x7FFF + ((v.u >> 16) & 1);   // RNE
    return (unsigned short)(r >> 16);
}
__device__ __forceinline__ float b2f(unsigned short u) {
    union { unsigned u; float f; } v; v.u = ((unsigned)u) << 16;
    return v.f;
}

__device__ __forceinline__ int qbucket(int cnt) {
    int qc = ((cnt + 4) & ~3) >> 2;
    return qc < NBK - 1 ? qc : NBK - 1;
}

// ---------------- setup kernels ----------------

// ONE 32-bit atomic per edge: pack = count<<24 | w*2^16 (max deg ~70 << 255, wsum < 2^24).
// combo padded to 1 node / 64B line. r5 evidence: 64-bit atomics write-through at
// 32B sectors (WRITE_SIZE 56MB = 1.6M x 32B), 20.6 G atomics/s. This tests
// sector-bandwidth-bound (32-bit helps) vs op-rate-bound (null).
__global__ __launch_bounds__(256) void rank_kernel(const int* __restrict__ dst,
                                                   const float* __restrict__ w,
                                                   unsigned int* __restrict__ combo,
                                                   int* __restrict__ rank, int E) {
    int e = blockIdx.x * 256 + threadIdx.x;
    if (e < E) {
        int d = dst[e];
        unsigned pack = (1u << 24) | (unsigned)(w[e] * WSCALE);
        unsigned old = atomicAdd(&combo[(size_t)d * 16], pack);
        rank[e] = (int)(old >> 24);
    }
}

// fused: dinv per original node + per-block degree histogram (one combo read)
__global__ __launch_bounds__(256) void dinv_hist_kernel(const unsigned int* __restrict__ combo,
                                                        float* __restrict__ dinv,
                                                        int* __restrict__ blockhist, int n) {
    __shared__ int lh[NBK];
    int t = threadIdx.x;
    if (t < NBK) lh[t] = 0;
    __syncthreads();
    int d = blockIdx.x * 256 + t;
    if (d < n) {
        unsigned cw = combo[(size_t)d * 16];
        int cnt = (int)(cw >> 24);
        float degv = (float)(cw & 0xffffffu) * (1.0f / WSCALE);
        dinv[d] = rsqrtf(degv + 1.0f);
        atomicAdd(&lh[qbucket(cnt)], 1);
    }
    __syncthreads();
    if (t < NBK) blockhist[blockIdx.x * NBK + t] = lh[t];
}

// one block PER BUCKET: exclusive prefix of its per-block counts + bucket total
__global__ __launch_bounds__(256) void bin_prescan_kernel(const int* __restrict__ blockhist,
                                                          int* __restrict__ blockpre,
                                                          int* __restrict__ tot, int nblk) {
    int bkt = blockIdx.x;
    int t = threadIdx.x, lane = t & 63, w = t >> 6;
    __shared__ int wsum[4];
    __shared__ int s_carry;
    if (t == 0) s_carry = 0;
    __syncthreads();
    for (int base = 0; base < nblk; base += 256) {
        int i = base + t;
        int v = (i < nblk) ? blockhist[i * NBK + bkt] : 0;
        int x = v;
        for (int off = 1; off < 64; off <<= 1) {
            int u = __shfl_up(x, off);
            if (lane >= off) x += u;
        }
        if (lane == 63) wsum[w] = x;
        __syncthreads();
        if (t == 0) {
            int a = wsum[0];
            wsum[0] = 0;
            for (int k = 1; k < 4; ++k) { int b = wsum[k]; wsum[k] = a; a += b; }
            wsum[0] = 0;
        }
        __syncthreads();
        int carry = s_carry;
        int woff = wsum[w];
        if (i < nblk) blockpre[i * NBK + bkt] = carry + woff + x - v;
        __syncthreads();
        if (t == 255) s_carry = carry + woff + x;
        __syncthreads();
    }
    if (t == 0) tot[bkt] = s_carry;
}

// single wave: base[b] = sum_{b' > b} tot[b']  (descending buckets first)
__global__ __launch_bounds__(64) void bin_suffix_kernel(const int* __restrict__ tot,
                                                        int* __restrict__ base) {
    int t = threadIdx.x;
    int v = tot[t];
    int s = v;
    for (int off = 1; off < 64; off <<= 1) {
        int u = __shfl_down(s, off);
        if (t + off < 64) s += u;
    }
    base[t] = s - v;
}

// assign slots via LDS cursors; also record each slot's padded quad length (linear later)
__global__ __launch_bounds__(256) void bin_scatter_kernel(const unsigned int* __restrict__ combo,
                                                          const int* __restrict__ base,
                                                          const int* __restrict__ blockpre,
                                                          int* __restrict__ perm,
                                                          int* __restrict__ posod,
                                                          int* __restrict__ qlen, int n) {
    __shared__ int lcur[NBK];
    int t = threadIdx.x;
    if (t < NBK) lcur[t] = base[t] + blockpre[blockIdx.x * NBK + t];
    __syncthreads();
    int d = blockIdx.x * 256 + t;
    if (d < n) {
        int cnt = (int)(combo[(size_t)d * 16] >> 24);
        int pos = atomicAdd(&lcur[qbucket(cnt)], 1);
        perm[pos] = d;
        posod[d] = pos;
        qlen[pos] = (cnt + 4) & ~3;
    }
}

// ---- row_ptr over permuted slots: 3-kernel multi-block scan ----

// block-local inclusive scan of qlen -> row_ptr[i+1]; block totals -> bsum
__global__ __launch_bounds__(1024) void scan_local_kernel(const int* __restrict__ qlen,
                                                          int* __restrict__ row_ptr,
                                                          int* __restrict__ bsum, int n) {
    int tid = threadIdx.x, lane = tid & 63, w = tid >> 6;
    __shared__ int wsum[16];
    int i = blockIdx.x * 1024 + tid;
    int v = (i < n) ? qlen[i] : 0;
    int x = v;
    for (int off = 1; off < 64; off <<= 1) {
        int t = __shfl_up(x, off);
        if (lane >= off) x += t;
    }
    if (lane == 63) wsum[w] = x;
    __syncthreads();
    if (w == 0 && lane < 16) {
        int s = wsum[lane];
        for (int off = 1; off < 16; off <<= 1) {
            int t = __shfl_up(s, off, 16);
            if (lane >= off) s += t;
        }
        wsum[lane] = s;
    }
    __syncthreads();
    int woff = (w > 0) ? wsum[w - 1] : 0;
    if (i < n) row_ptr[i + 1] = woff + x;
    if (tid == 0) bsum[blockIdx.x] = wsum[15];
}

// single wave: exclusive scan of block sums (carry loop handles nb > 64); row_ptr[0] = 0
__global__ __launch_bounds__(64) void scan_mid_kernel(int* __restrict__ bsum,
                                                      int* __restrict__ row_ptr, int nb) {
    int t = threadIdx.x;
    int carry = 0;
    for (int base = 0; base < nb; base += 64) {
        int idx = base + t;
        int v = (idx < nb) ? bsum[idx] : 0;
        int x = v;
        for (int off = 1; off < 64; off <<= 1) {
            int u = __shfl_up(x, off);
            if (t >= off) x += u;
        }
        if (idx < nb) bsum[idx] = carry + x - v;
        carry += __shfl(x, 63);
    }
    if (t == 0) row_ptr[0] = 0;
}

// add block offsets
__global__ __launch_bounds__(1024) void scan_add_kernel(const int* __restrict__ bsum,
                                                        int* __restrict__ row_ptr, int n) {
    int i = blockIdx.x * 1024 + threadIdx.x;
    if (i < n) row_ptr[i + 1] += bsum[blockIdx.x];
}

// self-edge (slot 0, weight dinv^2, src = own slot) + zero-weight pads
__global__ __launch_bounds__(256) void selfpad_kernel(const unsigned int* __restrict__ combo,
                                                      const int* __restrict__ row_ptr,
                                                      const int* __restrict__ posod,
                                                      const float* __restrict__ dinv,
                                                      unsigned int* __restrict__ edge, int n) {
    int d = blockIdx.x * 256 + threadIdx.x;
    if (d < n) {
        int cnt = (int)(combo[(size_t)d * 16] >> 24);
        int slot = posod[d];
        int j0 = row_ptr[slot], j1 = row_ptr[slot + 1];
        float di = dinv[d];
        edge[j0] = ((unsigned)f2b(di * di) << 16) | (unsigned)slot;
        for (int j = j0 + 1 + cnt; j < j1; ++j) edge[j] = (unsigned)slot;  // w = +0
    }
}

// atomic-free scatter into permuted CSR; record = wn(bf16)<<16 | srcslot(u16)
__global__ __launch_bounds__(256) void scatter2_kernel(
    const int* __restrict__ src, const int* __restrict__ dst,
    const float* __restrict__ w, const int* __restrict__ rank,
    const int* __restrict__ row_ptr, const int* __restrict__ posod,
    const float* __restrict__ dinv, unsigned int* __restrict__ edge, int E) {
    int e = blockIdx.x * 256 + threadIdx.x;
    if (e < E) {
        int d = dst[e], s = src[e];
        float wn = dinv[s] * w[e] * dinv[d];
        edge[row_ptr[posod[d]] + 1 + rank[e]] = ((unsigned)f2b(wn) << 16) | (unsigned)posod[s];
    }
}

// node f32 [N][F] (original order) -> bf16 slice-major [F/32][n][32] in SLOT order
__global__ __launch_bounds__(256) void cast_sliced_kernel(const float* __restrict__ in,
                                                          const int* __restrict__ perm,
                                                          unsigned short* __restrict__ out,
                                                          int n, int F) {
    int idx = blockIdx.x * 256 + threadIdx.x;
    if (idx < n * (F / 4)) {
        int f4 = idx * 4;
        int slot = f4 / F, f = f4 - slot * F;
        float4 v = *(const float4*)&in[(size_t)perm[slot] * F + f];
        short4v s = (short4v){(short)f2b(v.x), (short)f2b(v.y), (short)f2b(v.z), (short)f2b(v.w)};
        *(short4v*)&out[((size_t)(f >> 5) * n + slot) * 32 + (f & 31)] = s;
    }
}

// batched transpose+cast: Wt[l][n][k] = W[l][k][n], l in [0,nl)
__global__ __launch_bounds__(256) void wtransL_kernel(const float* __restrict__ W,
                                                      unsigned short* __restrict__ Wt,
                                                      int K, int Nc, int total) {
    int o = blockIdx.x * 256 + threadIdx.x;
    if (o < total) {
        int l = o / (K * Nc);
        int r = o - l * K * Nc;
        int n = r / K, k = r - n * K;
        Wt[o] = f2b(W[(size_t)l * K * Nc + (size_t)k * Nc + n]);
    }
}

// ---------------- bf16 MFMA GEMM, full-N strip: C[M,256] = A[M,K](bf16) @ Bt[256,K]^T ----

#define GST 88

template <bool SLICEOUT>
__global__ __launch_bounds__(256) void gemm_n256(const unsigned short* __restrict__ A,
                                                 const unsigned short* __restrict__ Bt,
                                                 unsigned short* __restrict__ Cout,
                                                 const float* __restrict__ bias,
                                                 int M, int K) {
    __shared__ __align__(16) short As[64 * GST];
    __shared__ __align__(16) short Bs[256 * GST];
    int t = threadIdx.x;
    int lane = t & 63, w = t >> 6;
    int quad = lane >> 4, l16 = lane & 15;
    int row0 = blockIdx.x * 64;

    float4v acc[16];
#pragma unroll
    for (int c = 0; c < 16; ++c) acc[c] = (float4v){0.f, 0.f, 0.f, 0.f};

    int arow = t >> 2, ak16 = (t & 3) * 16;
    int bcol0 = t >> 2, bko = (t & 3) * 16;

    for (int k_outer = 0; k_outer < K; k_outer += 64) {
        bool rowok = (row0 + arow) < M;
        const unsigned short* ap = &A[(size_t)(row0 + arow) * K + k_outer + ak16];
        uint4 z = make_uint4(0, 0, 0, 0);
        uint4 u0 = rowok ? *(const uint4*)ap : z;
        uint4 u1 = rowok ? *(const uint4*)(ap + 8) : z;
        *(uint4*)&As[arow * GST + ak16] = u0;
        *(uint4*)&As[arow * GST + ak16 + 8] = u1;
#pragma unroll
        for (int cb = 0; cb < 4; ++cb) {
            int col = bcol0 + 64 * cb;
            const unsigned short* bp = &Bt[(size_t)col * K + k_outer + bko];
#pragma unroll
            for (int u = 0; u < 2; ++u)
                *(uint4*)&Bs[col * GST + bko + u * 8] = *(const uint4*)&bp[u * 8];
        }
        __syncthreads();
#pragma unroll
        for (int k0 = 0; k0 < 64; k0 += 32) {
            short8 a = *(const short8*)&As[(w * 16 + l16) * GST + k0 + quad * 8];
#pragma unroll
            for (int c = 0; c < 16; ++c) {
                short8 b = *(const short8*)&Bs[(c * 16 + l16) * GST + k0 + quad * 8];
                acc[c] = __builtin_amdgcn_mfma_f32_16x16x32_bf16(a, b, acc[c], 0, 0, 0);
            }
        }
        __syncthreads();
    }
#pragma unroll
    for (int c = 0; c < 16; ++c) {
        int col = c * 16 + l16;
        float bcol = (!SLICEOUT) ? bias[col] : 0.0f;
#pragma unroll
        for (int r = 0; r < 4; ++r) {
            int row = row0 + w * 16 + quad * 4 + r;
            if (row < M) {
                if (SLICEOUT)
                    Cout[((size_t)(c >> 1) * M + row) * 32 + ((c & 1) << 4) + l16] = f2b(acc[c][r]);
                else
                    Cout[(size_t)row * 256 + col] = f2b(acc[c][r] + bcol);
            }
        }
    }
}

// ---------------- aggregation: 4-lane group per slot, slice-major table, LDS edges ------
// Slots degree-sorted (descending): 16 groups per wave see near-equal row lengths.
// slice = blockIdx & mask -> XCD-resident 3.2MB slice. 16 KB LDS edge stage.
//
// AT STRUCTURAL FLOOR (r0/r2/r4 A/B): gather rate ~11.2 TB/s from L2 invariant
// to occupancy (35-46%), loop structure (simple/MLP), LDS (16/32KB) -> L2-side
// random-64B-line service cap (~10 lines/cy/XCD). Line count (slices x E_pad)
// is invariant to slice-width reshuffles. Simple loop fastest; do not touch.

#define CAPQ 1024   // 4096 edges, 16 KB LDS

template <int CSH>
__global__ __launch_bounds__(256) void agg_grp(
    const unsigned short* __restrict__ tab0, const int* __restrict__ row_ptr,
    const unsigned int* __restrict__ edge, unsigned short* __restrict__ outb, int n) {
    __shared__ uint4v eq[CAPQ];
    int b = blockIdx.x;
    int s = b & ((1 << CSH) - 1);
    int grp = b >> CSH;
    int t = threadIdx.x;
    int d0 = grp * 64;
    int d = d0 + (t >> 2);

    const uint4v* e4p = (const uint4v*)edge;
    int qbase = row_ptr[d0] >> 2;
    int dmax = d0 + 64 < n ? d0 + 64 : n;
    int qcnt = (row_ptr[dmax] >> 2) - qbase;
    int qstage = qcnt < CAPQ ? qcnt : CAPQ;
    for (int i = t; i < qstage; i += 256) eq[i] = NT_LOAD(&e4p[qbase + i]);
    __syncthreads();

    if (d >= n) return;
    int fo = (t & 3) << 3;                    // feature offset within the 32-wide slice
    const unsigned short* tab = tab0 + (size_t)s * n * 32;

    int j = row_ptr[d] >> 2, j1 = row_ptr[d + 1] >> 2;
    int jmid = j1 < qbase + CAPQ ? j1 : qbase + CAPQ;

    float2v a2[4];
#pragma unroll
    for (int k = 0; k < 4; ++k) a2[k] = (float2v){0.f, 0.f};

    auto process = [&](uint4v e4) {
#pragma unroll
        for (int u = 0; u < 4; ++u) {
            unsigned e = e4[u];
            float wq = __int_as_float((int)(e & 0xffff0000u));
            float2v w2 = {wq, wq};
            unsigned off = ((e & 0xffffu) << 5) + (unsigned)fo;
            uint4 rr = *(const uint4*)(tab + off);
            unsigned uu0 = rr.x, uu1 = rr.y, uu2 = rr.z, uu3 = rr.w;
            float2v f0 = {__uint_as_float(uu0 << 16), __uint_as_float(uu0 & 0xffff0000u)};
            float2v f1 = {__uint_as_float(uu1 << 16), __uint_as_float(uu1 & 0xffff0000u)};
            float2v f2 = {__uint_as_float(uu2 << 16), __uint_as_float(uu2 & 0xffff0000u)};
            float2v f3 = {__uint_as_float(uu3 << 16), __uint_as_float(uu3 & 0xffff0000u)};
            a2[0] += f0 * w2;
            a2[1] += f1 * w2;
            a2[2] += f2 * w2;
            a2[3] += f3 * w2;
        }
    };

    for (; j + 2 <= jmid; j += 2) {
        uint4v e4a = eq[j - qbase];
        uint4v e4b = eq[j + 1 - qbase];
        process(e4a);
        process(e4b);
    }
    if (j < jmid) { process(eq[j - qbase]); ++j; }
    for (; j < j1; ++j) process(NT_LOAD(&e4p[j]));   // overflow fallback (first blocks only)

    ushort8 o;
#pragma unroll
    for (int k = 0; k < 4; ++k) {
        o[2 * k] = f2b(a2[k].x);
        o[2 * k + 1] = f2b(a2[k].y);
    }
    *(ushort8*)(outb + ((size_t)d << (5 + CSH)) + (s << 5) + fo) = o;
}

// ---------------- bias + LayerNorm + residual + ReLU (bf16 in, bf16 out) ----------------

__global__ __launch_bounds__(256) void ln_res_relu(
    const unsigned short* __restrict__ preln, const float* __restrict__ bias,
    const float* __restrict__ g, const float* __restrict__ lb,
    const unsigned short* __restrict__ res, unsigned short* __restrict__ out, int n) {
    int wv = __builtin_amdgcn_readfirstlane(threadIdx.x >> 6);
    int d = blockIdx.x * 4 + wv;
    if (d >= n) return;
    int l = threadIdx.x & 63;
    int fo = l * 4;
    ushort4 pv = *(const ushort4*)&preln[(size_t)d * 256 + fo];
    float4 bb = *(const float4*)&bias[fo];
    float v[4] = {b2f(pv.x) + bb.x, b2f(pv.y) + bb.y, b2f(pv.z) + bb.z, b2f(pv.w) + bb.w};
    float s4 = v[0] + v[1] + v[2] + v[3];
#pragma unroll
    for (int off = 1; off < 64; off <<= 1) s4 += __shfl_xor(s4, off);
    float mu = s4 * (1.0f / 256.0f);
    float dv[4];
    float qs = 0.f;
#pragma unroll
    for (int j = 0; j < 4; ++j) { dv[j] = v[j] - mu; qs += dv[j] * dv[j]; }
#pragma unroll
    for (int off = 1; off < 64; off <<= 1) qs += __shfl_xor(qs, off);
    float rs = rsqrtf(qs * (1.0f / 256.0f) + EPS);

    float4 gg = *(const float4*)&g[fo];
    float4 lbv = *(const float4*)&lb[fo];
    ushort4 rr4 = *(const ushort4*)&res[(size_t)d * 256 + fo];
    float ggv[4] = {gg.x, gg.y, gg.z, gg.w};
    float lbvv[4] = {lbv.x, lbv.y, lbv.z, lbv.w};
    float rrv[4] = {b2f(rr4.x), b2f(rr4.y), b2f(rr4.z), b2f(rr4.w)};
    ushort4 o;
    unsigned short* op = (unsigned short*)&o;
#pragma unroll
    for (int j = 0; j < 4; ++j) {
        float x = dv[j] * rs * ggv[j] + lbvv[j] + rrv[j];
        op[j] = f2b(x > 0.f ? x : 0.f);
    }
    *(ushort4*)&out[(size_t)d * 256 + fo] = o;
}

// ---------------- head ----------------

__global__ __launch_bounds__(256) void colsum_kernel(const unsigned short* __restrict__ x,
                                                     float* __restrict__ sums, int n) {
    int h = threadIdx.x;
    float acc = 0.0f;
    for (int r = blockIdx.x; r < n; r += gridDim.x) acc += b2f(x[(size_t)r * 256 + h]);
    atomicAdd(&sums[h], acc);
}

__global__ __launch_bounds__(64) void final_kernel(const float* __restrict__ sums,
                                                   const float* __restrict__ fcW,
                                                   const float* __restrict__ fcb,
                                                   float* __restrict__ out, float invN) {
    int lane = threadIdx.x;
    float p0 = 0.0f, p1 = 0.0f;
    for (int hh = lane; hh < 256; hh += 64) {
        float m = sums[hh];
        p0 += m * fcW[hh * 2 + 0];
        p1 += m * fcW[hh * 2 + 1];
    }
    for (int off = 32; off > 0; off >>= 1) {
        p0 += __shfl_down(p0, off);
        p1 += __shfl_down(p1, off);
    }
    if (lane == 0) {
        out[0] = p0 * invN + fcb[0];
        out[1] = p1 * invN + fcb[1];
    }
}

// ---------------- launch ----------------

extern "C" void kernel_launch(void* const* d_in, const int* in_sizes, int n_in,
                              void* d_out, int out_size, void* d_ws, size_t ws_size,
                              hipStream_t stream) {
    const float* node    = (const float*)d_in[0];
    const int*   edges   = (const int*)d_in[1];
    const float* eattr   = (const float*)d_in[2];
    const float* W1      = (const float*)d_in[3];
    const float* b1      = (const float*)d_in[4];
    const float* W_convs = (const float*)d_in[5];
    const float* b_convs = (const float*)d_in[6];
    const float* ln_g    = (const float*)d_in[7];
    const float* ln_b    = (const float*)d_in[8];
    const float* fc_W    = (const float*)d_in[9];
    const float* fc_b    = (const float*)d_in[10];
    float* out = (float*)d_out;

    const int H = in_sizes[4];           // 256
    const int F = in_sizes[3] / H;       // 128
    const int N = in_sizes[0] / F;       // 50000
    const int E = in_sizes[2];           // 1600000
    const int L = in_sizes[6] / H;       // 3

    const int* src = edges;
    const int* dst = edges + E;

    char* p = (char*)d_ws;
    auto alloc = [&](size_t bytes) {
        char* r = p;
        p += (bytes + 255) & ~(size_t)255;
        return r;
    };
    int nblk = (N + 255) / 256;
    int nb1024 = (N + 1023) / 1024;
    // zeroed region: padded combo (64B/node) + colsums, contiguous
    unsigned int* combo = (unsigned int*)alloc((size_t)N * 64);
    float* colsums = (float*)alloc((size_t)H * 4);
    size_t zero_bytes = (size_t)((char*)colsums - (char*)combo) + (((size_t)H * 4 + 255) & ~(size_t)255);
    int*   blockhist = (int*)alloc((size_t)nblk * NBK * 4);
    int*   blockpre  = (int*)alloc((size_t)nblk * NBK * 4);
    int*   tot       = (int*)alloc((size_t)NBK * 4);
    int*   bbase     = (int*)alloc((size_t)NBK * 4);
    int*   perm    = (int*)alloc((size_t)N * 4);
    int*   posod   = (int*)alloc((size_t)N * 4);
    int*   qlen    = (int*)alloc((size_t)N * 4);
    float* dinv    = (float*)alloc((size_t)N * 4);
    int*   row_ptr = (int*)alloc((size_t)(N + 1) * 4);
    int*   bsum    = (int*)alloc((size_t)nb1024 * 4);
    unsigned int* edge = (unsigned int*)alloc(((size_t)E + 4 * (size_t)N + 64) * 4);
    unsigned short* Wt1 = (unsigned short*)alloc((size_t)H * F * 2);
    unsigned short* Wtc = (unsigned short*)alloc((size_t)L * H * H * 2);
    unsigned short* xw  = (unsigned short*)alloc((size_t)N * H * 2);   // sliced [8][N][32]
    unsigned short* preln = (unsigned short*)alloc((size_t)N * H * 2); // row-major [N][256]
    unsigned short* bufA  = (unsigned short*)alloc((size_t)N * H * 2); // bf16 x
    unsigned short* bufB  = (unsigned short*)alloc((size_t)N * H * 2); // bf16 x
    // aliases (dead before their slabs' first real use):
    int*            rank  = (int*)xw;                     // E*4 <= N*H*2
    unsigned short* nodeb = preln;                        // sliced [4][N][32] = N*128 shorts
    unsigned short* aggn  = preln + (size_t)N * F;        // bf16 [N][128] row-major

    hipMemsetAsync(combo, 0, zero_bytes, stream);

    int gE = (E + 255) / 256;
    rank_kernel<<<gE, 256, 0, stream>>>(dst, eattr, combo, rank, E);
    dinv_hist_kernel<<<nblk, 256, 0, stream>>>(combo, dinv, blockhist, N);
    bin_prescan_kernel<<<NBK, 256, 0, stream>>>(blockhist, blockpre, tot, nblk);
    bin_suffix_kernel<<<1, 64, 0, stream>>>(tot, bbase);
    bin_scatter_kernel<<<nblk, 256, 0, stream>>>(combo, bbase, blockpre, perm, posod, qlen, N);
    scan_local_kernel<<<nb1024, 1024, 0, stream>>>(qlen, row_ptr, bsum, N);
    scan_mid_kernel<<<1, 64, 0, stream>>>(bsum, row_ptr, nb1024);
    scan_add_kernel<<<nb1024, 1024, 0, stream>>>(bsum, row_ptr, N);
    selfpad_kernel<<<nblk, 256, 0, stream>>>(combo, row_ptr, posod, dinv, edge, N);
    scatter2_kernel<<<gE, 256, 0, stream>>>(src, dst, eattr, rank, row_ptr, posod, dinv, edge, E);

    cast_sliced_kernel<<<(N * (F / 4) + 255) / 256, 256, 0, stream>>>(node, perm, nodeb, N, F);
    wtransL_kernel<<<(F * H + 255) / 256, 256, 0, stream>>>(W1, Wt1, F, H, F * H);
    wtransL_kernel<<<(L * H * H + 255) / 256, 256, 0, stream>>>(W_convs, Wtc, H, H, L * H * H);

    int ngrp64 = (N + 63) / 64;
    int lngrid = (N + 3) / 4;
    int ggrid = (N + 63) / 64;

    // layer 1 (slot space): aggn = agg(node); x1 = aggn @ W1 + b1 (bf16)
    agg_grp<2><<<4 * ngrp64, 256, 0, stream>>>(nodeb, row_ptr, edge, aggn, N);
    gemm_n256<false><<<ggrid, 256, 0, stream>>>(aggn, Wt1, bufA, b1, N, F);

    unsigned short* x = bufA;
    unsigned short* other = bufB;
    for (int i = 0; i < L; ++i) {
        gemm_n256<true><<<ggrid, 256, 0, stream>>>(x, Wtc + (size_t)i * H * H, xw, nullptr, N, H);
        agg_grp<3><<<8 * ngrp64, 256, 0, stream>>>(xw, row_ptr, edge, preln, N);
        ln_res_relu<<<lngrid, 256, 0, stream>>>(preln, b_convs + (size_t)i * H,
                                                ln_g + (size_t)i * H, ln_b + (size_t)i * H,
                                                x, other, N);
        unsigned short* t = x; x = other; other = t;
    }

    colsum_kernel<<<256, 256, 0, stream>>>(x, colsums, N);
    final_kernel<<<1, 64, 0, stream>>>(colsums, fc_W, fc_b, out, 1.0f / (float)N);
}

// Round 8
// 628.261 us; speedup vs baseline: 1.1909x; 1.0872x over previous
//
#include <hip/hip_runtime.h>

#define EPS 1e-5f
#define WSCALE 65536.0f       // 2^16 fixed-point for degree accumulation (24-bit field)
#define NBK 64                // degree buckets (qc clamped)

typedef __attribute__((ext_vector_type(8))) short short8;
typedef __attribute__((ext_vector_type(4))) short short4v;
typedef __attribute__((ext_vector_type(4))) float float4v;
typedef __attribute__((ext_vector_type(2))) float float2v;
typedef __attribute__((ext_vector_type(8))) unsigned short ushort8;
typedef __attribute__((ext_vector_type(4))) unsigned int uint4v;

#if __has_builtin(__builtin_nontemporal_load)
#define NT_LOAD(p) __builtin_nontemporal_load(p)
#else
#define NT_LOAD(p) (*(p))
#endif

__device__ __forceinline__ unsigned short f2b(float f) {
    union { float f; unsigned u; } v; v.f = f;
    unsigned r = v.u + 0x7FFF + ((v.u >> 16) & 1);   // RNE
    return (unsigned short)(r >> 16);
}
__device__ __forceinline__ float b2f(unsigned short u) {
    union { unsigned u; float f; } v; v.u = ((unsigned)u) << 16;
    return v.f;
}

__device__ __forceinline__ int qbucket(int cnt) {
    int qc = ((cnt + 4) & ~3) >> 2;
    return qc < NBK - 1 ? qc : NBK - 1;
}

// ---------------- setup kernels ----------------

// ONE 32-bit atomic per edge: pack = count<<24 | w*2^16 (max deg ~70 << 255, wsum < 2^24).
// combo padded to 1 node / 64B line. (r7: 32-bit atomic beat 64-bit by ~10us.)
__global__ __launch_bounds__(256) void rank_kernel(const int* __restrict__ dst,
                                                   const float* __restrict__ w,
                                                   unsigned int* __restrict__ combo,
                                                   int* __restrict__ rank, int E) {
    int e = blockIdx.x * 256 + threadIdx.x;
    if (e < E) {
        int d = dst[e];
        unsigned pack = (1u << 24) | (unsigned)(w[e] * WSCALE);
        unsigned old = atomicAdd(&combo[(size_t)d * 16], pack);
        rank[e] = (int)(old >> 24);
    }
}

// fused: dinv per original node + per-block degree histogram (one combo read)
__global__ __launch_bounds__(256) void dinv_hist_kernel(const unsigned int* __restrict__ combo,
                                                        float* __restrict__ dinv,
                                                        int* __restrict__ blockhist, int n) {
    __shared__ int lh[NBK];
    int t = threadIdx.x;
    if (t < NBK) lh[t] = 0;
    __syncthreads();
    int d = blockIdx.x * 256 + t;
    if (d < n) {
        unsigned cw = combo[(size_t)d * 16];
        int cnt = (int)(cw >> 24);
        float degv = (float)(cw & 0xffffffu) * (1.0f / WSCALE);
        dinv[d] = rsqrtf(degv + 1.0f);
        atomicAdd(&lh[qbucket(cnt)], 1);
    }
    __syncthreads();
    if (t < NBK) blockhist[blockIdx.x * NBK + t] = lh[t];
}

// one block PER BUCKET: exclusive prefix of its per-block counts + bucket total
__global__ __launch_bounds__(256) void bin_prescan_kernel(const int* __restrict__ blockhist,
                                                          int* __restrict__ blockpre,
                                                          int* __restrict__ tot, int nblk) {
    int bkt = blockIdx.x;
    int t = threadIdx.x, lane = t & 63, w = t >> 6;
    __shared__ int wsum[4];
    __shared__ int s_carry;
    if (t == 0) s_carry = 0;
    __syncthreads();
    for (int base = 0; base < nblk; base += 256) {
        int i = base + t;
        int v = (i < nblk) ? blockhist[i * NBK + bkt] : 0;
        int x = v;
        for (int off = 1; off < 64; off <<= 1) {
            int u = __shfl_up(x, off);
            if (lane >= off) x += u;
        }
        if (lane == 63) wsum[w] = x;
        __syncthreads();
        if (t == 0) {
            int a = wsum[0];
            wsum[0] = 0;
            for (int k = 1; k < 4; ++k) { int b = wsum[k]; wsum[k] = a; a += b; }
            wsum[0] = 0;
        }
        __syncthreads();
        int carry = s_carry;
        int woff = wsum[w];
        if (i < nblk) blockpre[i * NBK + bkt] = carry + woff + x - v;
        __syncthreads();
        if (t == 255) s_carry = carry + woff + x;
        __syncthreads();
    }
    if (t == 0) tot[bkt] = s_carry;
}

// single wave: base[b] = sum_{b' > b} tot[b']  (descending buckets first)
__global__ __launch_bounds__(64) void bin_suffix_kernel(const int* __restrict__ tot,
                                                        int* __restrict__ base) {
    int t = threadIdx.x;
    int v = tot[t];
    int s = v;
    for (int off = 1; off < 64; off <<= 1) {
        int u = __shfl_down(s, off);
        if (t + off < 64) s += u;
    }
    base[t] = s - v;
}

// assign slots via LDS cursors; also record each slot's padded quad length (linear later)
__global__ __launch_bounds__(256) void bin_scatter_kernel(const unsigned int* __restrict__ combo,
                                                          const int* __restrict__ base,
                                                          const int* __restrict__ blockpre,
                                                          int* __restrict__ perm,
                                                          int* __restrict__ posod,
                                                          int* __restrict__ qlen, int n) {
    __shared__ int lcur[NBK];
    int t = threadIdx.x;
    if (t < NBK) lcur[t] = base[t] + blockpre[blockIdx.x * NBK + t];
    __syncthreads();
    int d = blockIdx.x * 256 + t;
    if (d < n) {
        int cnt = (int)(combo[(size_t)d * 16] >> 24);
        int pos = atomicAdd(&lcur[qbucket(cnt)], 1);
        perm[pos] = d;
        posod[d] = pos;
        qlen[pos] = (cnt + 4) & ~3;
    }
}

// ---- row_ptr over permuted slots: 3-kernel multi-block scan ----

__global__ __launch_bounds__(1024) void scan_local_kernel(const int* __restrict__ qlen,
                                                          int* __restrict__ row_ptr,
                                                          int* __restrict__ bsum, int n) {
    int tid = threadIdx.x, lane = tid & 63, w = tid >> 6;
    __shared__ int wsum[16];
    int i = blockIdx.x * 1024 + tid;
    int v = (i < n) ? qlen[i] : 0;
    int x = v;
    for (int off = 1; off < 64; off <<= 1) {
        int t = __shfl_up(x, off);
        if (lane >= off) x += t;
    }
    if (lane == 63) wsum[w] = x;
    __syncthreads();
    if (w == 0 && lane < 16) {
        int s = wsum[lane];
        for (int off = 1; off < 16; off <<= 1) {
            int t = __shfl_up(s, off, 16);
            if (lane >= off) s += t;
        }
        wsum[lane] = s;
    }
    __syncthreads();
    int woff = (w > 0) ? wsum[w - 1] : 0;
    if (i < n) row_ptr[i + 1] = woff + x;
    if (tid == 0) bsum[blockIdx.x] = wsum[15];
}

__global__ __launch_bounds__(64) void scan_mid_kernel(int* __restrict__ bsum,
                                                      int* __restrict__ row_ptr, int nb) {
    int t = threadIdx.x;
    int carry = 0;
    for (int base = 0; base < nb; base += 64) {
        int idx = base + t;
        int v = (idx < nb) ? bsum[idx] : 0;
        int x = v;
        for (int off = 1; off < 64; off <<= 1) {
            int u = __shfl_up(x, off);
            if (t >= off) x += u;
        }
        if (idx < nb) bsum[idx] = carry + x - v;
        carry += __shfl(x, 63);
    }
    if (t == 0) row_ptr[0] = 0;
}

__global__ __launch_bounds__(1024) void scan_add_kernel(const int* __restrict__ bsum,
                                                        int* __restrict__ row_ptr, int n) {
    int i = blockIdx.x * 1024 + threadIdx.x;
    if (i < n) row_ptr[i + 1] += bsum[blockIdx.x];
}

// self-edge (slot 0, weight dinv^2, src = own slot) + zero-weight pads
__global__ __launch_bounds__(256) void selfpad_kernel(const unsigned int* __restrict__ combo,
                                                      const int* __restrict__ row_ptr,
                                                      const int* __restrict__ posod,
                                                      const float* __restrict__ dinv,
                                                      unsigned int* __restrict__ edge, int n) {
    int d = blockIdx.x * 256 + threadIdx.x;
    if (d < n) {
        int cnt = (int)(combo[(size_t)d * 16] >> 24);
        int slot = posod[d];
        int j0 = row_ptr[slot], j1 = row_ptr[slot + 1];
        float di = dinv[d];
        edge[j0] = ((unsigned)f2b(di * di) << 16) | (unsigned)slot;
        for (int j = j0 + 1 + cnt; j < j1; ++j) edge[j] = (unsigned)slot;  // w = +0
    }
}

// atomic-free scatter into permuted CSR; record = wn(bf16)<<16 | srcslot(u16)
__global__ __launch_bounds__(256) void scatter2_kernel(
    const int* __restrict__ src, const int* __restrict__ dst,
    const float* __restrict__ w, const int* __restrict__ rank,
    const int* __restrict__ row_ptr, const int* __restrict__ posod,
    const float* __restrict__ dinv, unsigned int* __restrict__ edge, int E) {
    int e = blockIdx.x * 256 + threadIdx.x;
    if (e < E) {
        int d = dst[e], s = src[e];
        float wn = dinv[s] * w[e] * dinv[d];
        edge[row_ptr[posod[d]] + 1 + rank[e]] = ((unsigned)f2b(wn) << 16) | (unsigned)posod[s];
    }
}

// node f32 [N][F] (original order) -> fp8 e4m3 slice-major [F/64][n][64] in SLOT order
__global__ __launch_bounds__(256) void cast_sliced_fp8(const float* __restrict__ in,
                                                       const int* __restrict__ perm,
                                                       unsigned char* __restrict__ out,
                                                       int n, int F) {
    int idx = blockIdx.x * 256 + threadIdx.x;
    if (idx < n * (F / 4)) {
        int f4 = idx * 4;
        int slot = f4 / F, f = f4 - slot * F;
        float4 v = *(const float4*)&in[(size_t)perm[slot] * F + f];
        int p = __builtin_amdgcn_cvt_pk_fp8_f32(v.x, v.y, 0, false);
        p = __builtin_amdgcn_cvt_pk_fp8_f32(v.z, v.w, p, true);
        *(unsigned int*)&out[((size_t)(f >> 6) * n + slot) * 64 + (f & 63)] = (unsigned)p;
    }
}

// batched transpose+cast: Wt[l][n][k] = W[l][k][n], l in [0,nl)
__global__ __launch_bounds__(256) void wtransL_kernel(const float* __restrict__ W,
                                                      unsigned short* __restrict__ Wt,
                                                      int K, int Nc, int total) {
    int o = blockIdx.x * 256 + threadIdx.x;
    if (o < total) {
        int l = o / (K * Nc);
        int r = o - l * K * Nc;
        int n = r / K, k = r - n * K;
        Wt[o] = f2b(W[(size_t)l * K * Nc + (size_t)k * Nc + n]);
    }
}

// ---------------- bf16 MFMA GEMM, full-N strip: C[M,256] = A[M,K](bf16) @ Bt[256,K]^T ----
// SLICEOUT: epilogue packs f32 acc -> fp8 e4m3 sliced [4][M][64] via shfl-combine
// (cols are spread across l16 lanes; 3 shfl levels build a 16B store on l16==0).

#define GST 88

template <bool SLICEOUT>
__global__ __launch_bounds__(256) void gemm_n256(const unsigned short* __restrict__ A,
                                                 const unsigned short* __restrict__ Bt,
                                                 unsigned short* __restrict__ Cout,
                                                 const float* __restrict__ bias,
                                                 int M, int K) {
    __shared__ __align__(16) short As[64 * GST];
    __shared__ __align__(16) short Bs[256 * GST];
    int t = threadIdx.x;
    int lane = t & 63, w = t >> 6;
    int quad = lane >> 4, l16 = lane & 15;
    int row0 = blockIdx.x * 64;

    float4v acc[16];
#pragma unroll
    for (int c = 0; c < 16; ++c) acc[c] = (float4v){0.f, 0.f, 0.f, 0.f};

    int arow = t >> 2, ak16 = (t & 3) * 16;
    int bcol0 = t >> 2, bko = (t & 3) * 16;

    for (int k_outer = 0; k_outer < K; k_outer += 64) {
        bool rowok = (row0 + arow) < M;
        const unsigned short* ap = &A[(size_t)(row0 + arow) * K + k_outer + ak16];
        uint4 z = make_uint4(0, 0, 0, 0);
        uint4 u0 = rowok ? *(const uint4*)ap : z;
        uint4 u1 = rowok ? *(const uint4*)(ap + 8) : z;
        *(uint4*)&As[arow * GST + ak16] = u0;
        *(uint4*)&As[arow * GST + ak16 + 8] = u1;
#pragma unroll
        for (int cb = 0; cb < 4; ++cb) {
            int col = bcol0 + 64 * cb;
            const unsigned short* bp = &Bt[(size_t)col * K + k_outer + bko];
#pragma unroll
            for (int u = 0; u < 2; ++u)
                *(uint4*)&Bs[col * GST + bko + u * 8] = *(const uint4*)&bp[u * 8];
        }
        __syncthreads();
#pragma unroll
        for (int k0 = 0; k0 < 64; k0 += 32) {
            short8 a = *(const short8*)&As[(w * 16 + l16) * GST + k0 + quad * 8];
#pragma unroll
            for (int c = 0; c < 16; ++c) {
                short8 b = *(const short8*)&Bs[(c * 16 + l16) * GST + k0 + quad * 8];
                acc[c] = __builtin_amdgcn_mfma_f32_16x16x32_bf16(a, b, acc[c], 0, 0, 0);
            }
        }
        __syncthreads();
    }
    if (SLICEOUT) {
        unsigned char* c8 = (unsigned char*)Cout;
#pragma unroll
        for (int c = 0; c < 16; ++c) {
#pragma unroll
            for (int r = 0; r < 4; ++r) {
                float v = acc[c][r];
                float vn = __shfl_xor(v, 1);
                int pair = __builtin_amdgcn_cvt_pk_fp8_f32(v, vn, 0, false);
                int p2 = __shfl_xor(pair, 2);
                int quad32 = (pair & 0xffff) | (p2 << 16);
                int b4 = __shfl_xor(quad32, 4);
                int b8 = __shfl_xor(quad32, 8);
                int b12 = __shfl_xor(b4, 8);
                int row = row0 + w * 16 + quad * 4 + r;
                if (l16 == 0 && row < M) {
                    uint4 ov = make_uint4((unsigned)quad32, (unsigned)b4,
                                          (unsigned)b8, (unsigned)b12);
                    *(uint4*)&c8[((size_t)(c >> 2) * M + row) * 64 + ((c & 3) << 4)] = ov;
                }
            }
        }
    } else {
#pragma unroll
        for (int c = 0; c < 16; ++c) {
            int col = c * 16 + l16;
            float bcol = bias[col];
#pragma unroll
            for (int r = 0; r < 4; ++r) {
                int row = row0 + w * 16 + quad * 4 + r;
                if (row < M) Cout[(size_t)row * 256 + col] = f2b(acc[c][r] + bcol);
            }
        }
    }
}

// ---------------- aggregation: 4-lane group per slot, fp8 slice-major table -------------
// Slots degree-sorted (descending). slice = blockIdx & mask -> XCD-resident 3.2MB slice.
// 16 KB LDS edge stage. agg is L2 random-64B-line REQUEST-bound (r0-r7 A/B: rate
// invariant to occupancy/loop/LDS). fp8 e4m3 halves lines/edge: conv 8->4, L1 4->2.
// Accumulate f32 (native v_cvt_pk_f32_fp8 decode), output bf16.

#define CAPQ 1024   // 4096 edges, 16 KB LDS

template <int CSH>   // 2^CSH slices of 64 fp8 features each
__global__ __launch_bounds__(256) void agg_grp(
    const unsigned char* __restrict__ tab0, const int* __restrict__ row_ptr,
    const unsigned int* __restrict__ edge, unsigned short* __restrict__ outb, int n) {
    __shared__ uint4v eq[CAPQ];
    int b = blockIdx.x;
    int s = b & ((1 << CSH) - 1);
    int grp = b >> CSH;
    int t = threadIdx.x;
    int d0 = grp * 64;
    int d = d0 + (t >> 2);

    const uint4v* e4p = (const uint4v*)edge;
    int qbase = row_ptr[d0] >> 2;
    int dmax = d0 + 64 < n ? d0 + 64 : n;
    int qcnt = (row_ptr[dmax] >> 2) - qbase;
    int qstage = qcnt < CAPQ ? qcnt : CAPQ;
    for (int i = t; i < qstage; i += 256) eq[i] = NT_LOAD(&e4p[qbase + i]);
    __syncthreads();

    if (d >= n) return;
    int fo = (t & 3) << 4;                    // byte (=feature) offset in 64-wide slice
    const unsigned char* tab = tab0 + (size_t)s * n * 64;

    int j = row_ptr[d] >> 2, j1 = row_ptr[d + 1] >> 2;
    int jmid = j1 < qbase + CAPQ ? j1 : qbase + CAPQ;

    float2v a2[8];
#pragma unroll
    for (int k = 0; k < 8; ++k) a2[k] = (float2v){0.f, 0.f};

    auto process = [&](uint4v e4) {
#pragma unroll
        for (int u = 0; u < 4; ++u) {
            unsigned e = e4[u];
            float wq = __int_as_float((int)(e & 0xffff0000u));
            float2v w2 = {wq, wq};
            unsigned off = ((e & 0xffffu) << 6) + (unsigned)fo;
            uint4 rr = *(const uint4*)(tab + off);
#pragma unroll
            for (int k = 0; k < 4; ++k) {
                unsigned uu = (&rr.x)[k];
                float2v lo = __builtin_amdgcn_cvt_pk_f32_fp8(uu, false);
                float2v hi = __builtin_amdgcn_cvt_pk_f32_fp8(uu, true);
                a2[2 * k] += lo * w2;
                a2[2 * k + 1] += hi * w2;
            }
        }
    };

    for (; j + 2 <= jmid; j += 2) {
        uint4v e4a = eq[j - qbase];
        uint4v e4b = eq[j + 1 - qbase];
        process(e4a);
        process(e4b);
    }
    if (j < jmid) { process(eq[j - qbase]); ++j; }
    for (; j < j1; ++j) process(NT_LOAD(&e4p[j]));   // overflow fallback (first blocks only)

    ushort8 o0, o1;
#pragma unroll
    for (int k = 0; k < 4; ++k) {
        o0[2 * k] = f2b(a2[k].x);
        o0[2 * k + 1] = f2b(a2[k].y);
        o1[2 * k] = f2b(a2[4 + k].x);
        o1[2 * k + 1] = f2b(a2[4 + k].y);
    }
    size_t obase = ((size_t)d << (6 + CSH)) + (s << 6) + fo;   // feature index, row=64<<CSH
    *(ushort8*)(outb + obase) = o0;
    *(ushort8*)(outb + obase + 8) = o1;
}

// ---------------- bias + LayerNorm + residual + ReLU (bf16 in, bf16 out) ----------------

__global__ __launch_bounds__(256) void ln_res_relu(
    const unsigned short* __restrict__ preln, const float* __restrict__ bias,
    const float* __restrict__ g, const float* __restrict__ lb,
    const unsigned short* __restrict__ res, unsigned short* __restrict__ out, int n) {
    int wv = __builtin_amdgcn_readfirstlane(threadIdx.x >> 6);
    int d = blockIdx.x * 4 + wv;
    if (d >= n) return;
    int l = threadIdx.x & 63;
    int fo = l * 4;
    ushort4 pv = *(const ushort4*)&preln[(size_t)d * 256 + fo];
    float4 bb = *(const float4*)&bias[fo];
    float v[4] = {b2f(pv.x) + bb.x, b2f(pv.y) + bb.y, b2f(pv.z) + bb.z, b2f(pv.w) + bb.w};
    float s4 = v[0] + v[1] + v[2] + v[3];
#pragma unroll
    for (int off = 1; off < 64; off <<= 1) s4 += __shfl_xor(s4, off);
    float mu = s4 * (1.0f / 256.0f);
    float dv[4];
    float qs = 0.f;
#pragma unroll
    for (int j = 0; j < 4; ++j) { dv[j] = v[j] - mu; qs += dv[j] * dv[j]; }
#pragma unroll
    for (int off = 1; off < 64; off <<= 1) qs += __shfl_xor(qs, off);
    float rs = rsqrtf(qs * (1.0f / 256.0f) + EPS);

    float4 gg = *(const float4*)&g[fo];
    float4 lbv = *(const float4*)&lb[fo];
    ushort4 rr4 = *(const ushort4*)&res[(size_t)d * 256 + fo];
    float ggv[4] = {gg.x, gg.y, gg.z, gg.w};
    float lbvv[4] = {lbv.x, lbv.y, lbv.z, lbv.w};
    float rrv[4] = {b2f(rr4.x), b2f(rr4.y), b2f(rr4.z), b2f(rr4.w)};
    ushort4 o;
    unsigned short* op = (unsigned short*)&o;
#pragma unroll
    for (int j = 0; j < 4; ++j) {
        float x = dv[j] * rs * ggv[j] + lbvv[j] + rrv[j];
        op[j] = f2b(x > 0.f ? x : 0.f);
    }
    *(ushort4*)&out[(size_t)d * 256 + fo] = o;
}

// ---------------- head ----------------

__global__ __launch_bounds__(256) void colsum_kernel(const unsigned short* __restrict__ x,
                                                     float* __restrict__ sums, int n) {
    int h = threadIdx.x;
    float acc = 0.0f;
    for (int r = blockIdx.x; r < n; r += gridDim.x) acc += b2f(x[(size_t)r * 256 + h]);
    atomicAdd(&sums[h], acc);
}

__global__ __launch_bounds__(64) void final_kernel(const float* __restrict__ sums,
                                                   const float* __restrict__ fcW,
                                                   const float* __restrict__ fcb,
                                                   float* __restrict__ out, float invN) {
    int lane = threadIdx.x;
    float p0 = 0.0f, p1 = 0.0f;
    for (int hh = lane; hh < 256; hh += 64) {
        float m = sums[hh];
        p0 += m * fcW[hh * 2 + 0];
        p1 += m * fcW[hh * 2 + 1];
    }
    for (int off = 32; off > 0; off >>= 1) {
        p0 += __shfl_down(p0, off);
        p1 += __shfl_down(p1, off);
    }
    if (lane == 0) {
        out[0] = p0 * invN + fcb[0];
        out[1] = p1 * invN + fcb[1];
    }
}

// ---------------- launch ----------------

extern "C" void kernel_launch(void* const* d_in, const int* in_sizes, int n_in,
                              void* d_out, int out_size, void* d_ws, size_t ws_size,
                              hipStream_t stream) {
    const float* node    = (const float*)d_in[0];
    const int*   edges   = (const int*)d_in[1];
    const float* eattr   = (const float*)d_in[2];
    const float* W1      = (const float*)d_in[3];
    const float* b1      = (const float*)d_in[4];
    const float* W_convs = (const float*)d_in[5];
    const float* b_convs = (const float*)d_in[6];
    const float* ln_g    = (const float*)d_in[7];
    const float* ln_b    = (const float*)d_in[8];
    const float* fc_W    = (const float*)d_in[9];
    const float* fc_b    = (const float*)d_in[10];
    float* out = (float*)d_out;

    const int H = in_sizes[4];           // 256
    const int F = in_sizes[3] / H;       // 128
    const int N = in_sizes[0] / F;       // 50000
    const int E = in_sizes[2];           // 1600000
    const int L = in_sizes[6] / H;       // 3

    const int* src = edges;
    const int* dst = edges + E;

    char* p = (char*)d_ws;
    auto alloc = [&](size_t bytes) {
        char* r = p;
        p += (bytes + 255) & ~(size_t)255;
        return r;
    };
    int nblk = (N + 255) / 256;
    int nb1024 = (N + 1023) / 1024;
    // zeroed region: padded combo (64B/node) + colsums, contiguous
    unsigned int* combo = (unsigned int*)alloc((size_t)N * 64);
    float* colsums = (float*)alloc((size_t)H * 4);
    size_t zero_bytes = (size_t)((char*)colsums - (char*)combo) + (((size_t)H * 4 + 255) & ~(size_t)255);
    int*   blockhist = (int*)alloc((size_t)nblk * NBK * 4);
    int*   blockpre  = (int*)alloc((size_t)nblk * NBK * 4);
    int*   tot       = (int*)alloc((size_t)NBK * 4);
    int*   bbase     = (int*)alloc((size_t)NBK * 4);
    int*   perm    = (int*)alloc((size_t)N * 4);
    int*   posod   = (int*)alloc((size_t)N * 4);
    int*   qlen    = (int*)alloc((size_t)N * 4);
    float* dinv    = (float*)alloc((size_t)N * 4);
    int*   row_ptr = (int*)alloc((size_t)(N + 1) * 4);
    int*   bsum    = (int*)alloc((size_t)nb1024 * 4);
    unsigned int* edge = (unsigned int*)alloc(((size_t)E + 4 * (size_t)N + 64) * 4);
    unsigned short* Wt1 = (unsigned short*)alloc((size_t)H * F * 2);
    unsigned short* Wtc = (unsigned short*)alloc((size_t)L * H * H * 2);
    unsigned char*  xw  = (unsigned char*)alloc((size_t)N * H);        // fp8 sliced [4][N][64]
    unsigned short* preln = (unsigned short*)alloc((size_t)N * H * 2); // row-major [N][256]
    unsigned short* bufA  = (unsigned short*)alloc((size_t)N * H * 2); // bf16 x
    unsigned short* bufB  = (unsigned short*)alloc((size_t)N * H * 2); // bf16 x
    // aliases (dead before their slabs' first real use):
    int*            rank  = (int*)xw;                     // E*4 <= N*H
    unsigned char*  nodeb = (unsigned char*)preln;        // fp8 sliced [2][N][64] = N*128 B
    unsigned short* aggn  = preln + (size_t)N * F;        // bf16 [N][128] row-major (12.8MB in)

    hipMemsetAsync(combo, 0, zero_bytes, stream);

    int gE = (E + 255) / 256;
    rank_kernel<<<gE, 256, 0, stream>>>(dst, eattr, combo, rank, E);
    dinv_hist_kernel<<<nblk, 256, 0, stream>>>(combo, dinv, blockhist, N);
    bin_prescan_kernel<<<NBK, 256, 0, stream>>>(blockhist, blockpre, tot, nblk);
    bin_suffix_kernel<<<1, 64, 0, stream>>>(tot, bbase);
    bin_scatter_kernel<<<nblk, 256, 0, stream>>>(combo, bbase, blockpre, perm, posod, qlen, N);
    scan_local_kernel<<<nb1024, 1024, 0, stream>>>(qlen, row_ptr, bsum, N);
    scan_mid_kernel<<<1, 64, 0, stream>>>(bsum, row_ptr, nb1024);
    scan_add_kernel<<<nb1024, 1024, 0, stream>>>(bsum, row_ptr, N);
    selfpad_kernel<<<nblk, 256, 0, stream>>>(combo, row_ptr, posod, dinv, edge, N);
    scatter2_kernel<<<gE, 256, 0, stream>>>(src, dst, eattr, rank, row_ptr, posod, dinv, edge, E);

    cast_sliced_fp8<<<(N * (F / 4) + 255) / 256, 256, 0, stream>>>(node, perm, nodeb, N, F);
    wtransL_kernel<<<(F * H + 255) / 256, 256, 0, stream>>>(W1, Wt1, F, H, F * H);
    wtransL_kernel<<<(L * H * H + 255) / 256, 256, 0, stream>>>(W_convs, Wtc, H, H, L * H * H);

    int ngrp64 = (N + 63) / 64;
    int lngrid = (N + 3) / 4;
    int ggrid = (N + 63) / 64;

    // layer 1 (slot space): aggn = agg(node); x1 = aggn @ W1 + b1 (bf16)
    agg_grp<1><<<2 * ngrp64, 256, 0, stream>>>(nodeb, row_ptr, edge, aggn, N);
    gemm_n256<false><<<ggrid, 256, 0, stream>>>(aggn, Wt1, bufA, b1, N, F);

    unsigned short* x = bufA;
    unsigned short* other = bufB;
    for (int i = 0; i < L; ++i) {
        gemm_n256<true><<<ggrid, 256, 0, stream>>>(x, Wtc + (size_t)i * H * H,
                                                   (unsigned short*)xw, nullptr, N, H);
        agg_grp<2><<<4 * ngrp64, 256, 0, stream>>>(xw, row_ptr, edge, preln, N);
        ln_res_relu<<<lngrid, 256, 0, stream>>>(preln, b_convs + (size_t)i * H,
                                                ln_g + (size_t)i * H, ln_b + (size_t)i * H,
                                                x, other, N);
        unsigned short* t = x; x = other; other = t;
    }

    colsum_kernel<<<256, 256, 0, stream>>>(x, colsums, N);
    final_kernel<<<1, 64, 0, stream>>>(colsums, fc_W, fc_b, out, 1.0f / (float)N);
}

// Round 9
// 626.487 us; speedup vs baseline: 1.1943x; 1.0028x over previous
//
#include <hip/hip_runtime.h>

#define EPS 1e-5f
#define WSCALE 65536.0f       // 2^16 fixed-point for degree accumulation (24-bit field)
#define NBK 64                // degree buckets (qc clamped)

typedef __attribute__((ext_vector_type(8))) short short8;
typedef __attribute__((ext_vector_type(4))) short short4v;
typedef __attribute__((ext_vector_type(4))) float float4v;
typedef __attribute__((ext_vector_type(2))) float float2v;
typedef __attribute__((ext_vector_type(8))) unsigned short ushort8;
typedef __attribute__((ext_vector_type(4))) unsigned int uint4v;

#if __has_builtin(__builtin_nontemporal_load)
#define NT_LOAD(p) __builtin_nontemporal_load(p)
#else
#define NT_LOAD(p) (*(p))
#endif

__device__ __forceinline__ unsigned short f2b(float f) {
    union { float f; unsigned u; } v; v.f = f;
    unsigned r = v.u + 0x7FFF + ((v.u >> 16) & 1);   // RNE
    return (unsigned short)(r >> 16);
}
__device__ __forceinline__ float b2f(unsigned short u) {
    union { unsigned u; float f; } v; v.u = ((unsigned)u) << 16;
    return v.f;
}

__device__ __forceinline__ int qbucket(int cnt) {
    int qc = ((cnt + 4) & ~3) >> 2;
    return qc < NBK - 1 ? qc : NBK - 1;
}

// ---------------- setup kernels ----------------

// ONE 32-bit atomic per edge: pack = count<<24 | w*2^16 (max deg ~70 << 255, wsum < 2^24).
// combo DENSELY packed (4B/node): r8 showed WRITE_SIZE = 1.6M x 32B sectors with 64B
// padding (each atomic its own sector, 875 GB/s write-through = the bottleneck).
// Dense packing -> 8 nodes/sector, memory-side coalescing of repeated sector flushes,
// and coalesced reads in the three consumer kernels.
__global__ __launch_bounds__(256) void rank_kernel(const int* __restrict__ dst,
                                                   const float* __restrict__ w,
                                                   unsigned int* __restrict__ combo,
                                                   int* __restrict__ rank, int E) {
    int e = blockIdx.x * 256 + threadIdx.x;
    if (e < E) {
        int d = dst[e];
        unsigned pack = (1u << 24) | (unsigned)(w[e] * WSCALE);
        unsigned old = atomicAdd(&combo[d], pack);
        rank[e] = (int)(old >> 24);
    }
}

// fused: dinv per original node + per-block degree histogram (one combo read)
__global__ __launch_bounds__(256) void dinv_hist_kernel(const unsigned int* __restrict__ combo,
                                                        float* __restrict__ dinv,
                                                        int* __restrict__ blockhist, int n) {
    __shared__ int lh[NBK];
    int t = threadIdx.x;
    if (t < NBK) lh[t] = 0;
    __syncthreads();
    int d = blockIdx.x * 256 + t;
    if (d < n) {
        unsigned cw = combo[d];
        int cnt = (int)(cw >> 24);
        float degv = (float)(cw & 0xffffffu) * (1.0f / WSCALE);
        dinv[d] = rsqrtf(degv + 1.0f);
        atomicAdd(&lh[qbucket(cnt)], 1);
    }
    __syncthreads();
    if (t < NBK) blockhist[blockIdx.x * NBK + t] = lh[t];
}

// one block PER BUCKET: exclusive prefix of its per-block counts + bucket total
__global__ __launch_bounds__(256) void bin_prescan_kernel(const int* __restrict__ blockhist,
                                                          int* __restrict__ blockpre,
                                                          int* __restrict__ tot, int nblk) {
    int bkt = blockIdx.x;
    int t = threadIdx.x, lane = t & 63, w = t >> 6;
    __shared__ int wsum[4];
    __shared__ int s_carry;
    if (t == 0) s_carry = 0;
    __syncthreads();
    for (int base = 0; base < nblk; base += 256) {
        int i = base + t;
        int v = (i < nblk) ? blockhist[i * NBK + bkt] : 0;
        int x = v;
        for (int off = 1; off < 64; off <<= 1) {
            int u = __shfl_up(x, off);
            if (lane >= off) x += u;
        }
        if (lane == 63) wsum[w] = x;
        __syncthreads();
        if (t == 0) {
            int a = wsum[0];
            wsum[0] = 0;
            for (int k = 1; k < 4; ++k) { int b = wsum[k]; wsum[k] = a; a += b; }
            wsum[0] = 0;
        }
        __syncthreads();
        int carry = s_carry;
        int woff = wsum[w];
        if (i < nblk) blockpre[i * NBK + bkt] = carry + woff + x - v;
        __syncthreads();
        if (t == 255) s_carry = carry + woff + x;
        __syncthreads();
    }
    if (t == 0) tot[bkt] = s_carry;
}

// single wave: base[b] = sum_{b' > b} tot[b']  (descending buckets first)
__global__ __launch_bounds__(64) void bin_suffix_kernel(const int* __restrict__ tot,
                                                        int* __restrict__ base) {
    int t = threadIdx.x;
    int v = tot[t];
    int s = v;
    for (int off = 1; off < 64; off <<= 1) {
        int u = __shfl_down(s, off);
        if (t + off < 64) s += u;
    }
    base[t] = s - v;
}

// assign slots via LDS cursors; also record each slot's padded quad length (linear later)
__global__ __launch_bounds__(256) void bin_scatter_kernel(const unsigned int* __restrict__ combo,
                                                          const int* __restrict__ base,
                                                          const int* __restrict__ blockpre,
                                                          int* __restrict__ perm,
                                                          int* __restrict__ posod,
                                                          int* __restrict__ qlen, int n) {
    __shared__ int lcur[NBK];
    int t = threadIdx.x;
    if (t < NBK) lcur[t] = base[t] + blockpre[blockIdx.x * NBK + t];
    __syncthreads();
    int d = blockIdx.x * 256 + t;
    if (d < n) {
        int cnt = (int)(combo[d] >> 24);
        int pos = atomicAdd(&lcur[qbucket(cnt)], 1);
        perm[pos] = d;
        posod[d] = pos;
        qlen[pos] = (cnt + 4) & ~3;
    }
}

// ---- row_ptr over permuted slots: 3-kernel multi-block scan ----

__global__ __launch_bounds__(1024) void scan_local_kernel(const int* __restrict__ qlen,
                                                          int* __restrict__ row_ptr,
                                                          int* __restrict__ bsum, int n) {
    int tid = threadIdx.x, lane = tid & 63, w = tid >> 6;
    __shared__ int wsum[16];
    int i = blockIdx.x * 1024 + tid;
    int v = (i < n) ? qlen[i] : 0;
    int x = v;
    for (int off = 1; off < 64; off <<= 1) {
        int t = __shfl_up(x, off);
        if (lane >= off) x += t;
    }
    if (lane == 63) wsum[w] = x;
    __syncthreads();
    if (w == 0 && lane < 16) {
        int s = wsum[lane];
        for (int off = 1; off < 16; off <<= 1) {
            int t = __shfl_up(s, off, 16);
            if (lane >= off) s += t;
        }
        wsum[lane] = s;
    }
    __syncthreads();
    int woff = (w > 0) ? wsum[w - 1] : 0;
    if (i < n) row_ptr[i + 1] = woff + x;
    if (tid == 0) bsum[blockIdx.x] = wsum[15];
}

__global__ __launch_bounds__(64) void scan_mid_kernel(int* __restrict__ bsum,
                                                      int* __restrict__ row_ptr, int nb) {
    int t = threadIdx.x;
    int carry = 0;
    for (int base = 0; base < nb; base += 64) {
        int idx = base + t;
        int v = (idx < nb) ? bsum[idx] : 0;
        int x = v;
        for (int off = 1; off < 64; off <<= 1) {
            int u = __shfl_up(x, off);
            if (t >= off) x += u;
        }
        if (idx < nb) bsum[idx] = carry + x - v;
        carry += __shfl(x, 63);
    }
    if (t == 0) row_ptr[0] = 0;
}

__global__ __launch_bounds__(1024) void scan_add_kernel(const int* __restrict__ bsum,
                                                        int* __restrict__ row_ptr, int n) {
    int i = blockIdx.x * 1024 + threadIdx.x;
    if (i < n) row_ptr[i + 1] += bsum[blockIdx.x];
}

// self-edge (slot 0, weight dinv^2, src = own slot) + zero-weight pads
__global__ __launch_bounds__(256) void selfpad_kernel(const unsigned int* __restrict__ combo,
                                                      const int* __restrict__ row_ptr,
                                                      const int* __restrict__ posod,
                                                      const float* __restrict__ dinv,
                                                      unsigned int* __restrict__ edge, int n) {
    int d = blockIdx.x * 256 + threadIdx.x;
    if (d < n) {
        int cnt = (int)(combo[d] >> 24);
        int slot = posod[d];
        int j0 = row_ptr[slot], j1 = row_ptr[slot + 1];
        float di = dinv[d];
        edge[j0] = ((unsigned)f2b(di * di) << 16) | (unsigned)slot;
        for (int j = j0 + 1 + cnt; j < j1; ++j) edge[j] = (unsigned)slot;  // w = +0
    }
}

// atomic-free scatter into permuted CSR; record = wn(bf16)<<16 | srcslot(u16)
__global__ __launch_bounds__(256) void scatter2_kernel(
    const int* __restrict__ src, const int* __restrict__ dst,
    const float* __restrict__ w, const int* __restrict__ rank,
    const int* __restrict__ row_ptr, const int* __restrict__ posod,
    const float* __restrict__ dinv, unsigned int* __restrict__ edge, int E) {
    int e = blockIdx.x * 256 + threadIdx.x;
    if (e < E) {
        int d = dst[e], s = src[e];
        float wn = dinv[s] * w[e] * dinv[d];
        edge[row_ptr[posod[d]] + 1 + rank[e]] = ((unsigned)f2b(wn) << 16) | (unsigned)posod[s];
    }
}

// node f32 [N][F] (original order) -> fp8 e4m3 slice-major [F/64][n][64] in SLOT order
__global__ __launch_bounds__(256) void cast_sliced_fp8(const float* __restrict__ in,
                                                       const int* __restrict__ perm,
                                                       unsigned char* __restrict__ out,
                                                       int n, int F) {
    int idx = blockIdx.x * 256 + threadIdx.x;
    if (idx < n * (F / 4)) {
        int f4 = idx * 4;
        int slot = f4 / F, f = f4 - slot * F;
        float4 v = *(const float4*)&in[(size_t)perm[slot] * F + f];
        int p = __builtin_amdgcn_cvt_pk_fp8_f32(v.x, v.y, 0, false);
        p = __builtin_amdgcn_cvt_pk_fp8_f32(v.z, v.w, p, true);
        *(unsigned int*)&out[((size_t)(f >> 6) * n + slot) * 64 + (f & 63)] = (unsigned)p;
    }
}

// batched transpose+cast: Wt[l][n][k] = W[l][k][n], l in [0,nl)
__global__ __launch_bounds__(256) void wtransL_kernel(const float* __restrict__ W,
                                                      unsigned short* __restrict__ Wt,
                                                      int K, int Nc, int total) {
    int o = blockIdx.x * 256 + threadIdx.x;
    if (o < total) {
        int l = o / (K * Nc);
        int r = o - l * K * Nc;
        int n = r / K, k = r - n * K;
        Wt[o] = f2b(W[(size_t)l * K * Nc + (size_t)k * Nc + n]);
    }
}

// ---------------- bf16 MFMA GEMM, full-N strip: C[M,256] = A[M,K](bf16) @ Bt[256,K]^T ----
// SLICEOUT: epilogue packs f32 acc -> fp8 e4m3 sliced [4][M][64] via shfl-combine
// (cols are spread across l16 lanes; 3 shfl levels build a 16B store on l16==0).

#define GST 88

template <bool SLICEOUT>
__global__ __launch_bounds__(256) void gemm_n256(const unsigned short* __restrict__ A,
                                                 const unsigned short* __restrict__ Bt,
                                                 unsigned short* __restrict__ Cout,
                                                 const float* __restrict__ bias,
                                                 int M, int K) {
    __shared__ __align__(16) short As[64 * GST];
    __shared__ __align__(16) short Bs[256 * GST];
    int t = threadIdx.x;
    int lane = t & 63, w = t >> 6;
    int quad = lane >> 4, l16 = lane & 15;
    int row0 = blockIdx.x * 64;

    float4v acc[16];
#pragma unroll
    for (int c = 0; c < 16; ++c) acc[c] = (float4v){0.f, 0.f, 0.f, 0.f};

    int arow = t >> 2, ak16 = (t & 3) * 16;
    int bcol0 = t >> 2, bko = (t & 3) * 16;

    for (int k_outer = 0; k_outer < K; k_outer += 64) {
        bool rowok = (row0 + arow) < M;
        const unsigned short* ap = &A[(size_t)(row0 + arow) * K + k_outer + ak16];
        uint4 z = make_uint4(0, 0, 0, 0);
        uint4 u0 = rowok ? *(const uint4*)ap : z;
        uint4 u1 = rowok ? *(const uint4*)(ap + 8) : z;
        *(uint4*)&As[arow * GST + ak16] = u0;
        *(uint4*)&As[arow * GST + ak16 + 8] = u1;
#pragma unroll
        for (int cb = 0; cb < 4; ++cb) {
            int col = bcol0 + 64 * cb;
            const unsigned short* bp = &Bt[(size_t)col * K + k_outer + bko];
#pragma unroll
            for (int u = 0; u < 2; ++u)
                *(uint4*)&Bs[col * GST + bko + u * 8] = *(const uint4*)&bp[u * 8];
        }
        __syncthreads();
#pragma unroll
        for (int k0 = 0; k0 < 64; k0 += 32) {
            short8 a = *(const short8*)&As[(w * 16 + l16) * GST + k0 + quad * 8];
#pragma unroll
            for (int c = 0; c < 16; ++c) {
                short8 b = *(const short8*)&Bs[(c * 16 + l16) * GST + k0 + quad * 8];
                acc[c] = __builtin_amdgcn_mfma_f32_16x16x32_bf16(a, b, acc[c], 0, 0, 0);
            }
        }
        __syncthreads();
    }
    if (SLICEOUT) {
        unsigned char* c8 = (unsigned char*)Cout;
#pragma unroll
        for (int c = 0; c < 16; ++c) {
#pragma unroll
            for (int r = 0; r < 4; ++r) {
                float v = acc[c][r];
                float vn = __shfl_xor(v, 1);
                int pair = __builtin_amdgcn_cvt_pk_fp8_f32(v, vn, 0, false);
                int p2 = __shfl_xor(pair, 2);
                int quad32 = (pair & 0xffff) | (p2 << 16);
                int b4 = __shfl_xor(quad32, 4);
                int b8 = __shfl_xor(quad32, 8);
                int b12 = __shfl_xor(b4, 8);
                int row = row0 + w * 16 + quad * 4 + r;
                if (l16 == 0 && row < M) {
                    uint4 ov = make_uint4((unsigned)quad32, (unsigned)b4,
                                          (unsigned)b8, (unsigned)b12);
                    *(uint4*)&c8[((size_t)(c >> 2) * M + row) * 64 + ((c & 3) << 4)] = ov;
                }
            }
        }
    } else {
#pragma unroll
        for (int c = 0; c < 16; ++c) {
            int col = c * 16 + l16;
            float bcol = bias[col];
#pragma unroll
            for (int r = 0; r < 4; ++r) {
                int row = row0 + w * 16 + quad * 4 + r;
                if (row < M) Cout[(size_t)row * 256 + col] = f2b(acc[c][r] + bcol);
            }
        }
    }
}

// ---------------- aggregation: 4-lane group per slot, fp8 slice-major table -------------
// Slots degree-sorted (descending). slice = blockIdx & mask -> XCD-resident 3.2MB slice.
// 16 KB LDS edge stage. agg is L2 random-64B-line REQUEST-bound (r0-r7 A/B: rate
// invariant to occupancy/loop/LDS). fp8 e4m3 halves lines/edge: conv 8->4, L1 4->2.
// Accumulate f32 (native v_cvt_pk_f32_fp8 decode), output bf16.

#define CAPQ 1024   // 4096 edges, 16 KB LDS

template <int CSH>   // 2^CSH slices of 64 fp8 features each
__global__ __launch_bounds__(256) void agg_grp(
    const unsigned char* __restrict__ tab0, const int* __restrict__ row_ptr,
    const unsigned int* __restrict__ edge, unsigned short* __restrict__ outb, int n) {
    __shared__ uint4v eq[CAPQ];
    int b = blockIdx.x;
    int s = b & ((1 << CSH) - 1);
    int grp = b >> CSH;
    int t = threadIdx.x;
    int d0 = grp * 64;
    int d = d0 + (t >> 2);

    const uint4v* e4p = (const uint4v*)edge;
    int qbase = row_ptr[d0] >> 2;
    int dmax = d0 + 64 < n ? d0 + 64 : n;
    int qcnt = (row_ptr[dmax] >> 2) - qbase;
    int qstage = qcnt < CAPQ ? qcnt : CAPQ;
    for (int i = t; i < qstage; i += 256) eq[i] = NT_LOAD(&e4p[qbase + i]);
    __syncthreads();

    if (d >= n) return;
    int fo = (t & 3) << 4;                    // byte (=feature) offset in 64-wide slice
    const unsigned char* tab = tab0 + (size_t)s * n * 64;

    int j = row_ptr[d] >> 2, j1 = row_ptr[d + 1] >> 2;
    int jmid = j1 < qbase + CAPQ ? j1 : qbase + CAPQ;

    float2v a2[8];
#pragma unroll
    for (int k = 0; k < 8; ++k) a2[k] = (float2v){0.f, 0.f};

    auto process = [&](uint4v e4) {
#pragma unroll
        for (int u = 0; u < 4; ++u) {
            unsigned e = e4[u];
            float wq = __int_as_float((int)(e & 0xffff0000u));
            float2v w2 = {wq, wq};
            unsigned off = ((e & 0xffffu) << 6) + (unsigned)fo;
            uint4 rr = *(const uint4*)(tab + off);
#pragma unroll
            for (int k = 0; k < 4; ++k) {
                unsigned uu = (&rr.x)[k];
                float2v lo = __builtin_amdgcn_cvt_pk_f32_fp8(uu, false);
                float2v hi = __builtin_amdgcn_cvt_pk_f32_fp8(uu, true);
                a2[2 * k] += lo * w2;
                a2[2 * k + 1] += hi * w2;
            }
        }
    };

    for (; j + 2 <= jmid; j += 2) {
        uint4v e4a = eq[j - qbase];
        uint4v e4b = eq[j + 1 - qbase];
        process(e4a);
        process(e4b);
    }
    if (j < jmid) { process(eq[j - qbase]); ++j; }
    for (; j < j1; ++j) process(NT_LOAD(&e4p[j]));   // overflow fallback (first blocks only)

    ushort8 o0, o1;
#pragma unroll
    for (int k = 0; k < 4; ++k) {
        o0[2 * k] = f2b(a2[k].x);
        o0[2 * k + 1] = f2b(a2[k].y);
        o1[2 * k] = f2b(a2[4 + k].x);
        o1[2 * k + 1] = f2b(a2[4 + k].y);
    }
    size_t obase = ((size_t)d << (6 + CSH)) + (s << 6) + fo;   // feature index, row=64<<CSH
    *(ushort8*)(outb + obase) = o0;
    *(ushort8*)(outb + obase + 8) = o1;
}

// ---------------- bias + LayerNorm + residual + ReLU (bf16 in, bf16 out) ----------------

__global__ __launch_bounds__(256) void ln_res_relu(
    const unsigned short* __restrict__ preln, const float* __restrict__ bias,
    const float* __restrict__ g, const float* __restrict__ lb,
    const unsigned short* __restrict__ res, unsigned short* __restrict__ out, int n) {
    int wv = __builtin_amdgcn_readfirstlane(threadIdx.x >> 6);
    int d = blockIdx.x * 4 + wv;
    if (d >= n) return;
    int l = threadIdx.x & 63;
    int fo = l * 4;
    ushort4 pv = *(const ushort4*)&preln[(size_t)d * 256 + fo];
    float4 bb = *(const float4*)&bias[fo];
    float v[4] = {b2f(pv.x) + bb.x, b2f(pv.y) + bb.y, b2f(pv.z) + bb.z, b2f(pv.w) + bb.w};
    float s4 = v[0] + v[1] + v[2] + v[3];
#pragma unroll
    for (int off = 1; off < 64; off <<= 1) s4 += __shfl_xor(s4, off);
    float mu = s4 * (1.0f / 256.0f);
    float dv[4];
    float qs = 0.f;
#pragma unroll
    for (int j = 0; j < 4; ++j) { dv[j] = v[j] - mu; qs += dv[j] * dv[j]; }
#pragma unroll
    for (int off = 1; off < 64; off <<= 1) qs += __shfl_xor(qs, off);
    float rs = rsqrtf(qs * (1.0f / 256.0f) + EPS);

    float4 gg = *(const float4*)&g[fo];
    float4 lbv = *(const float4*)&lb[fo];
    ushort4 rr4 = *(const ushort4*)&res[(size_t)d * 256 + fo];
    float ggv[4] = {gg.x, gg.y, gg.z, gg.w};
    float lbvv[4] = {lbv.x, lbv.y, lbv.z, lbv.w};
    float rrv[4] = {b2f(rr4.x), b2f(rr4.y), b2f(rr4.z), b2f(rr4.w)};
    ushort4 o;
    unsigned short* op = (unsigned short*)&o;
#pragma unroll
    for (int j = 0; j < 4; ++j) {
        float x = dv[j] * rs * ggv[j] + lbvv[j] + rrv[j];
        op[j] = f2b(x > 0.f ? x : 0.f);
    }
    *(ushort4*)&out[(size_t)d * 256 + fo] = o;
}

// ---------------- head ----------------

__global__ __launch_bounds__(256) void colsum_kernel(const unsigned short* __restrict__ x,
                                                     float* __restrict__ sums, int n) {
    int h = threadIdx.x;
    float acc = 0.0f;
    for (int r = blockIdx.x; r < n; r += gridDim.x) acc += b2f(x[(size_t)r * 256 + h]);
    atomicAdd(&sums[h], acc);
}

__global__ __launch_bounds__(64) void final_kernel(const float* __restrict__ sums,
                                                   const float* __restrict__ fcW,
                                                   const float* __restrict__ fcb,
                                                   float* __restrict__ out, float invN) {
    int lane = threadIdx.x;
    float p0 = 0.0f, p1 = 0.0f;
    for (int hh = lane; hh < 256; hh += 64) {
        float m = sums[hh];
        p0 += m * fcW[hh * 2 + 0];
        p1 += m * fcW[hh * 2 + 1];
    }
    for (int off = 32; off > 0; off >>= 1) {
        p0 += __shfl_down(p0, off);
        p1 += __shfl_down(p1, off);
    }
    if (lane == 0) {
        out[0] = p0 * invN + fcb[0];
        out[1] = p1 * invN + fcb[1];
    }
}

// ---------------- launch ----------------

extern "C" void kernel_launch(void* const* d_in, const int* in_sizes, int n_in,
                              void* d_out, int out_size, void* d_ws, size_t ws_size,
                              hipStream_t stream) {
    const float* node    = (const float*)d_in[0];
    const int*   edges   = (const int*)d_in[1];
    const float* eattr   = (const float*)d_in[2];
    const float* W1      = (const float*)d_in[3];
    const float* b1      = (const float*)d_in[4];
    const float* W_convs = (const float*)d_in[5];
    const float* b_convs = (const float*)d_in[6];
    const float* ln_g    = (const float*)d_in[7];
    const float* ln_b    = (const float*)d_in[8];
    const float* fc_W    = (const float*)d_in[9];
    const float* fc_b    = (const float*)d_in[10];
    float* out = (float*)d_out;

    const int H = in_sizes[4];           // 256
    const int F = in_sizes[3] / H;       // 128
    const int N = in_sizes[0] / F;       // 50000
    const int E = in_sizes[2];           // 1600000
    const int L = in_sizes[6] / H;       // 3

    const int* src = edges;
    const int* dst = edges + E;

    char* p = (char*)d_ws;
    auto alloc = [&](size_t bytes) {
        char* r = p;
        p += (bytes + 255) & ~(size_t)255;
        return r;
    };
    int nblk = (N + 255) / 256;
    int nb1024 = (N + 1023) / 1024;
    // zeroed region: densely packed combo (4B/node) + colsums, contiguous
    unsigned int* combo = (unsigned int*)alloc((size_t)N * 4);
    float* colsums = (float*)alloc((size_t)H * 4);
    size_t zero_bytes = (size_t)((char*)colsums - (char*)combo) + (((size_t)H * 4 + 255) & ~(size_t)255);
    int*   blockhist = (int*)alloc((size_t)nblk * NBK * 4);
    int*   blockpre  = (int*)alloc((size_t)nblk * NBK * 4);
    int*   tot       = (int*)alloc((size_t)NBK * 4);
    int*   bbase     = (int*)alloc((size_t)NBK * 4);
    int*   perm    = (int*)alloc((size_t)N * 4);
    int*   posod   = (int*)alloc((size_t)N * 4);
    int*   qlen    = (int*)alloc((size_t)N * 4);
    float* dinv    = (float*)alloc((size_t)N * 4);
    int*   row_ptr = (int*)alloc((size_t)(N + 1) * 4);
    int*   bsum    = (int*)alloc((size_t)nb1024 * 4);
    unsigned int* edge = (unsigned int*)alloc(((size_t)E + 4 * (size_t)N + 64) * 4);
    unsigned short* Wt1 = (unsigned short*)alloc((size_t)H * F * 2);
    unsigned short* Wtc = (unsigned short*)alloc((size_t)L * H * H * 2);
    unsigned char*  xw  = (unsigned char*)alloc((size_t)N * H);        // fp8 sliced [4][N][64]
    unsigned short* preln = (unsigned short*)alloc((size_t)N * H * 2); // row-major [N][256]
    unsigned short* bufA  = (unsigned short*)alloc((size_t)N * H * 2); // bf16 x
    unsigned short* bufB  = (unsigned short*)alloc((size_t)N * H * 2); // bf16 x
    // aliases (dead before their slabs' first real use):
    int*            rank  = (int*)xw;                     // E*4 <= N*H
    unsigned char*  nodeb = (unsigned char*)preln;        // fp8 sliced [2][N][64] = N*128 B
    unsigned short* aggn  = preln + (size_t)N * F;        // bf16 [N][128] row-major (12.8MB in)

    hipMemsetAsync(combo, 0, zero_bytes, stream);

    int gE = (E + 255) / 256;
    rank_kernel<<<gE, 256, 0, stream>>>(dst, eattr, combo, rank, E);
    dinv_hist_kernel<<<nblk, 256, 0, stream>>>(combo, dinv, blockhist, N);
    bin_prescan_kernel<<<NBK, 256, 0, stream>>>(blockhist, blockpre, tot, nblk);
    bin_suffix_kernel<<<1, 64, 0, stream>>>(tot, bbase);
    bin_scatter_kernel<<<nblk, 256, 0, stream>>>(combo, bbase, blockpre, perm, posod, qlen, N);
    scan_local_kernel<<<nb1024, 1024, 0, stream>>>(qlen, row_ptr, bsum, N);
    scan_mid_kernel<<<1, 64, 0, stream>>>(bsum, row_ptr, nb1024);
    scan_add_kernel<<<nb1024, 1024, 0, stream>>>(bsum, row_ptr, N);
    selfpad_kernel<<<nblk, 256, 0, stream>>>(combo, row_ptr, posod, dinv, edge, N);
    scatter2_kernel<<<gE, 256, 0, stream>>>(src, dst, eattr, rank, row_ptr, posod, dinv, edge, E);

    cast_sliced_fp8<<<(N * (F / 4) + 255) / 256, 256, 0, stream>>>(node, perm, nodeb, N, F);
    wtransL_kernel<<<(F * H + 255) / 256, 256, 0, stream>>>(W1, Wt1, F, H, F * H);
    wtransL_kernel<<<(L * H * H + 255) / 256, 256, 0, stream>>>(W_convs, Wtc, H, H, L * H * H);

    int ngrp64 = (N + 63) / 64;
    int lngrid = (N + 3) / 4;
    int ggrid = (N + 63) / 64;

    // layer 1 (slot space): aggn = agg(node); x1 = aggn @ W1 + b1 (bf16)
    agg_grp<1><<<2 * ngrp64, 256, 0, stream>>>(nodeb, row_ptr, edge, aggn, N);
    gemm_n256<false><<<ggrid, 256, 0, stream>>>(aggn, Wt1, bufA, b1, N, F);

    unsigned short* x = bufA;
    unsigned short* other = bufB;
    for (int i = 0; i < L; ++i) {
        gemm_n256<true><<<ggrid, 256, 0, stream>>>(x, Wtc + (size_t)i * H * H,
                                                   (unsigned short*)xw, nullptr, N, H);
        agg_grp<2><<<4 * ngrp64, 256, 0, stream>>>(xw, row_ptr, edge, preln, N);
        ln_res_relu<<<lngrid, 256, 0, stream>>>(preln, b_convs + (size_t)i * H,
                                                ln_g + (size_t)i * H, ln_b + (size_t)i * H,
                                                x, other, N);
        unsigned short* t = x; x = other; other = t;
    }

    colsum_kernel<<<256, 256, 0, stream>>>(x, colsums, N);
    final_kernel<<<1, 64, 0, stream>>>(colsums, fc_W, fc_b, out, 1.0f / (float)N);
}